// Round 7
// baseline (806.453 us; speedup 1.0000x reference)
//
#include <hip/hip_runtime.h>
#include <math.h>

// Problem constants
#define BB   16      // batch
#define IC   8       // in capsules
#define BI   128     // BB*IC
#define CIN  16      // conv in channels
#define WH   128     // input spatial
#define OWH  65      // output spatial (stride 2, pad 2, k 4)
#define NPIX (OWH*OWH)   // 4225
#define OC   8       // out capsules
#define COUT 16      // out channel per capsule
#define NOC  128     // OC*Cout
#define KTOT 256     // CIN*4*4
#define KC   64      // (fp32 fallback chunk)
#define NCHUNK 4
#define S_TOTAL (CIN*WH*WH)   // 262144 (per-bi s = (ci,row,col) extent)

// MFMA kernel: K chunked by 32 (one mfma-K per chunk), 8 chunks
#define NCHM 8

typedef unsigned short ushortT;
typedef __bf16 bf16x8 __attribute__((ext_vector_type(8)));
typedef float  f32x4  __attribute__((ext_vector_type(4)));

__device__ __forceinline__ ushortT f2bf(float f) {
    unsigned u = __float_as_uint(f);
    unsigned r = (u + 0x7fffu + ((u >> 16) & 1u)) >> 16;
    return (ushortT)r;
}

// DPP lane move within 16-lane rows (rows == our quads): VALU pipe, no LDS.
// 0xB1 = quad_perm[1,0,3,2] (xor1), 0x4E = quad_perm[2,3,0,1] (xor2),
// 0x124 = row_ror:4, 0x128 = row_ror:8 (rotation all-reduce over {+0,+4,+8,+12}).
template <int CTRL>
__device__ __forceinline__ float dppMov(float x) {
    return __int_as_float(__builtin_amdgcn_update_dpp(
        0, __float_as_int(x), CTRL, 0xF, 0xF, true));
}

// LDS-only barrier: orders LDS (lgkmcnt(0)) but does NOT drain vmcnt ->
// global prefetches/stores ride across (T4). sched_barrier per rule #18.
#define LDS_BARRIER() do {                                    \
    asm volatile("s_waitcnt lgkmcnt(0)" ::: "memory");        \
    __builtin_amdgcn_s_barrier();                             \
    __builtin_amdgcn_sched_barrier(0);                        \
} while (0)

// ---------------------------------------------------------------------------
// Pre-pass 1: x fp32 [bi][ci][row][col] -> bf16 TRANSPOSED xbfT[s][bi],
// s = (ci*WH+row)*WH+col (bi innermost => GEMM A-staging is coalesced).
// LDS-tiled: block = 64 consecutive s x all 128 bi.
// ---------------------------------------------------------------------------
__global__ void cvtT_kernel(const float* __restrict__ x,
                            ushortT* __restrict__ xbfT)
{
    __shared__ ushortT tile[64 * 136];   // [sIdx][bi], stride 136, XOR-swizzled
    const int t  = threadIdx.x;          // 0..255
    const int s0 = blockIdx.x * 64;      // 4096 blocks

    // load: 2048 float4 (128 bi x 16 s-quads); 8 per thread
#pragma unroll
    for (int k = 0; k < 8; ++k) {
        const int j  = t + k * 256;
        const int bi = j >> 4, s4 = j & 15;
        const float4 v = *(const float4*)(x + (size_t)bi * S_TOTAL + s0 + s4 * 4);
        const int si = s4 * 4;
        tile[(si    ) * 136 + (bi ^ (((si    ) & 15) << 3))] = f2bf(v.x);
        tile[(si + 1) * 136 + (bi ^ (((si + 1) & 15) << 3))] = f2bf(v.y);
        tile[(si + 2) * 136 + (bi ^ (((si + 2) & 15) << 3))] = f2bf(v.z);
        tile[(si + 3) * 136 + (bi ^ (((si + 3) & 15) << 3))] = f2bf(v.w);
    }
    __syncthreads();
    // store: 1024 x 16B (64 s x 16 bi-octets); 4 per thread, fully coalesced
#pragma unroll
    for (int k = 0; k < 4; ++k) {
        const int j  = t + k * 256;
        const int sI = j >> 4, g = j & 15;
        const uint4 val = *(const uint4*)&tile[sI * 136 + ((g ^ (sI & 15)) << 3)];
        *(uint4*)(xbfT + (size_t)(s0 + sI) * 128 + g * 8) = val;
    }
}

// ---------------------------------------------------------------------------
// Pre-pass 2: W fp32 [oc][k] -> bf16 prepacked fragment image:
//   Wbf[(kpg*128+oc)*8 + j]   (k = kpg*8 + j, kpg = 0..31)
// ---------------------------------------------------------------------------
__global__ void prep_w_kernel(const float* __restrict__ W,
                              ushortT* __restrict__ Wbf)
{
    int idx = blockIdx.x * 256 + threadIdx.x;   // 32768 total
    int oc = idx >> 8, k = idx & 255;
    int kpg = k >> 3, j = k & 7;
    Wbf[((size_t)kpg * 128 + oc) * 8 + j] = f2bf(W[idx]);
}

// ---------------------------------------------------------------------------
// Fused MFMA kernel, 512 threads (8 waves). Wave w owns a 64x32 C quadrant:
// rows [64*(w>>2), +64) x cols [32*(w&3), +32) as 4x2 tiles of 16x16.
//
// v8 (from v7, which passed on HW): TWO adjacent pixels per block, software
// pipelined: pixel1's A chunks 0-2 are loaded into registers BEFORE pixel0's
// routing and ride across it (routing barriers are lgkm-only; routing has no
// vmem deps). Unified GEMM schedule per pixel:
//   pre: chunks 0-2 in regs (aP0-2); issue loads 3,4 (aRr0/1);
//        store 0-2 -> bufs 0-2; barrier.
//   kc=0..7: compute buf kc%3 (chunk kc);
//     kc=1: store ch3->buf0, load ch5->aP0   (buf0 last read kc=0: 1 barrier)
//     kc=2: store ch4->buf1, load ch6->aP1
//     kc=3: store ch5->buf2, load ch7->aP2   (ch5 loaded @kc=1: 2 periods)
//     kc=4: store ch6->buf0;  kc=5: store ch7->buf1;  barrier each kc.
// p0/p1 windows overlap 50% of columns + share Wbf -> pixel1 loads L1/L2-hot.
// Routing identical to v7 (DPP reduce + fold). Data image identical (proven).
// C/D: col=lane&15 -> oc-col c, row=4*quad+reg -> (b,i). direct_out write.
// ---------------------------------------------------------------------------
__launch_bounds__(512, 8)
__global__ void capsconv_mfma(const ushortT* __restrict__ xbfT,
                              const ushortT* __restrict__ Wbf,
                              const float* __restrict__ bias,
                              float* __restrict__ outbuf,
                              const int direct_out)
{
    __shared__ __align__(16) ushortT As[3][4 * 128 * 8];   // 3 x 8 KB ring
    __shared__ float cijs[64];       // [o][i]
    __shared__ float bijs[64];       // [o][i] (wave 0 only)
    __shared__ float aTmp[16 * 64];  // [b][o*8+i]

    const int t  = threadIdx.x;      // 0..511
    const int g8 = blockIdx.x;       // 0..2119
    const int strip = g8 & 7;
    const int jj2   = g8 >> 3;               // 0..264
    const int p0 = strip * 529 + 2 * jj2;    // this block: p0 and maybe p0+1
    if (p0 >= NPIX) return;
    const bool p1ok = (2 * jj2 + 1 <= 528) && (p0 + 1 < NPIX);

    const int w  = t >> 6;       // wave id 0..7
    const int ln = t & 63;
    const int q  = ln >> 4;      // quad
    const int cL = ln & 15;      // lane col (c within tile)
    const int h  = q & 1;        // i-half
    const int mrow_base = 64 * (w >> 2);   // 0 or 64
    const int ncol_base = 32 * (w & 3);    // 0,32,64,96

    f32x4 acc[4][2];

    // ---- A staging map (thread-invariant parts) ----
    const int g     = t & 15;        // bi octet
    const int sI    = t >> 4;        // 0..31
    const int colw  = sI & 3;
    const int rowl  = (sI >> 2) & 3;
    const int cih   = sI >> 4;       // 0..1
    // LDS dest (bytes within As[buf]); bits 4-6 of wbase are zero.
    const int kpg   = cih * 2 + (rowl >> 1);
    const int jj    = (rowl & 1) * 4 + colw;
    const int wbase = (kpg * 128 + g * 8) * 16 + jj * 2;
    const int gk7   = g & 7;

    // fragment read byte offsets (swizzled), chunk-invariant
    int aRd[4];
#pragma unroll
    for (int mt = 0; mt < 4; ++mt) {
        const int by = (q * 128 + mrow_base + mt * 16 + cL) * 16;
        aRd[mt] = by ^ (((by >> 7) & 7) << 4);
    }

    uint4 aP0, aP1, aP2;   // prefetch regs (chunks 0-2, then 5-7)
    uint4 aRr0, aRr1;      // chunks 3,4

    auto mkAddr = [&](int pp, size_t& aoff, bool& okp) {
        const int ppx = pp / OWH, ppy = pp % OWH;
        const int srow2 = 2 * ppx - 2 + rowl;
        const int scol2 = 2 * ppy - 2 + colw;
        okp = (srow2 >= 0 && srow2 < WH && scol2 >= 0 && scol2 < WH);
        aoff = okp ? ((size_t)((cih * WH + srow2) * WH + scol2) * 128 + g * 8) : 0;
    };
    auto loadAx = [&](uint4& r, int kc, size_t aoff, bool okp) {
        r = make_uint4(0u, 0u, 0u, 0u);
        if (okp) r = *(const uint4*)(xbfT + aoff + (size_t)kc * (2 * WH * WH * 128));
    };
    auto storeA = [&](int buf, const uint4& r) {
        char* ab = (char*)&As[buf][0];
        const ushortT* av = (const ushortT*)&r;
#pragma unroll
        for (int c = 0; c < 8; ++c)
            *(ushortT*)(ab + wbase + ((c ^ gk7) << 4)) = av[c];
    };
    auto prefetch3 = [&](size_t aoff, bool okp) {
        loadAx(aP0, 0, aoff, okp);
        loadAx(aP1, 1, aoff, okp);
        loadAx(aP2, 2, aoff, okp);
    };

    auto gemm = [&](size_t aoff, bool okp) {
#pragma unroll
        for (int mt = 0; mt < 4; ++mt)
#pragma unroll
            for (int nt = 0; nt < 2; ++nt) acc[mt][nt] = (f32x4){0.f, 0.f, 0.f, 0.f};

        loadAx(aRr0, 3, aoff, okp);
        loadAx(aRr1, 4, aoff, okp);
        storeA(0, aP0);            // counted vmcnt waits land here
        storeA(1, aP1);
        storeA(2, aP2);
        LDS_BARRIER();

#pragma unroll
        for (int kc = 0; kc < NCHM; ++kc) {
            {
                const char* abase = (const char*)&As[kc % 3][0];
                bf16x8 af[4], bfr[2];
#pragma unroll
                for (int mt = 0; mt < 4; ++mt)
                    af[mt] = *(const bf16x8*)(abase + aRd[mt]);
                // B direct from global (L2-hot, no barrier dependency)
                const ushortT* bsrc = Wbf + kc * 4096 + (q * 128 + ncol_base + cL) * 8;
                bfr[0] = *(const bf16x8*)(bsrc);
                bfr[1] = *(const bf16x8*)(bsrc + 128);
#pragma unroll
                for (int mt = 0; mt < 4; ++mt)
#pragma unroll
                    for (int nt = 0; nt < 2; ++nt)
                        acc[mt][nt] = __builtin_amdgcn_mfma_f32_16x16x32_bf16(
                            af[mt], bfr[nt], acc[mt][nt], 0, 0, 0);
            }
            if (kc == 1)      { storeA(0, aRr0); loadAx(aP0, 5, aoff, okp); }
            else if (kc == 2) { storeA(1, aRr1); loadAx(aP1, 6, aoff, okp); }
            else if (kc == 3) { storeA(2, aP0);  loadAx(aP2, 7, aoff, okp); }
            else if (kc == 4) { storeA(0, aP1); }
            else if (kc == 5) { storeA(1, aP2); }
            LDS_BARRIER();
        }

        // bias epilogue
#pragma unroll
        for (int nt = 0; nt < 2; ++nt) {
            const float bv = bias[ncol_base + nt * 16 + cL];
#pragma unroll
            for (int mt = 0; mt < 4; ++mt) acc[mt][nt] += bv;
        }
    };

    // ---------------- dynamic routing (3 iters) ----------------
    auto routing = [&](int p) {
        for (int it = 0; it < 3; ++it) {
            float4 cf4[2];
            if (it == 0) {
#pragma unroll
                for (int nt = 0; nt < 2; ++nt)
                    cf4[nt] = make_float4(0.125f, 0.125f, 0.125f, 0.125f);
            } else {
#pragma unroll
                for (int nt = 0; nt < 2; ++nt)
                    cf4[nt] = *(const float4*)&cijs[(2 * (w & 3) + nt) * 8 + 4 * h];
            }

#pragma unroll
            for (int mt = 0; mt < 4; ++mt) {
                const int b = 8 * (w >> 2) + 2 * mt + (q >> 1);
#pragma unroll
                for (int nt = 0; nt < 2; ++nt) {
                    const int o = 2 * (w & 3) + nt;
                    const float4 cf = cf4[nt];
                    float sp = cf.x * acc[mt][nt][0] + cf.y * acc[mt][nt][1]
                             + cf.z * acc[mt][nt][2] + cf.w * acc[mt][nt][3];
                    float s = sp + __shfl_xor(sp, 16);
                    // ssq over the 16 cL lanes (DPP, VALU-only)
                    float ssq = s * s;
                    ssq += dppMov<0xB1>(ssq);
                    ssq += dppMov<0x4E>(ssq);
                    ssq += dppMov<0x124>(ssq);
                    ssq += dppMov<0x128>(ssq);
                    const float scale = sqrtf(ssq) * __builtin_amdgcn_rcpf(1.f + ssq);
                    const float vj = s * scale;

                    if (it == 2) {
                        if (q == 0 || q == 2) {
                            if (direct_out)
                                outbuf[(size_t)(b * NOC + o * 16 + cL) * NPIX + p] = vj;
                            else
                                outbuf[(size_t)p * 2048 + b * NOC + o * 16 + cL] = vj;
                        }
                    } else {
                        // fold: rows -> lanes; lane cL ends with row (cL&3)
                        f32x4 ap = acc[mt][nt] * vj;
                        const bool k1 = (cL & 1) != 0;
                        float e0 = k1 ? ap[1] : ap[0];
                        float o0 = k1 ? ap[0] : ap[1];
                        float e1 = k1 ? ap[3] : ap[2];
                        float o1 = k1 ? ap[2] : ap[3];
                        e0 += dppMov<0xB1>(o0);
                        e1 += dppMov<0xB1>(o1);
                        const bool k2 = (cL & 2) != 0;
                        float f0 = k2 ? e1 : e0;
                        float f1 = k2 ? e0 : e1;
                        f0 += dppMov<0x4E>(f1);
                        f0 += dppMov<0x124>(f0);
                        f0 += dppMov<0x128>(f0);
                        if (cL < 4)
                            aTmp[b * 64 + o * 8 + 4 * h + cL] = f0;
                    }
                }
            }
            if (it < 2) {
                LDS_BARRIER();   // aTmp writes visible (lgkm-only: no vmem deps)
                if (t < 64) {
                    float sum = 0.f;
#pragma unroll
                    for (int b = 0; b < BB; ++b) sum += aTmp[b * 64 + t];
                    float bij = (it == 0 ? 0.f : bijs[t]) + sum * (1.f / 16.f);
                    bijs[t] = bij;
                    float mx = bij;
                    mx = fmaxf(mx, __shfl_xor(mx, 1));
                    mx = fmaxf(mx, __shfl_xor(mx, 2));
                    mx = fmaxf(mx, __shfl_xor(mx, 4));
                    float e = __expf(bij - mx);
                    float se = e;
                    se += __shfl_xor(se, 1);
                    se += __shfl_xor(se, 2);
                    se += __shfl_xor(se, 4);
                    cijs[t] = e * __builtin_amdgcn_rcpf(se);
                }
                LDS_BARRIER();
            }
        }
    };

    // ---------------- 2-pixel pipeline ----------------
    size_t aoff0s, aoff1s;
    bool ok0, ok1;
    mkAddr(p0, aoff0s, ok0);

    prefetch3(aoff0s, ok0);          // pixel0 chunks 0-2 (cold)
    gemm(aoff0s, ok0);
    if (p1ok) {
        mkAddr(p0 + 1, aoff1s, ok1);
        prefetch3(aoff1s, ok1);      // pixel1 chunks 0-2: in flight across routing
    }
    routing(p0);
    if (p1ok) {
        gemm(aoff1s, ok1);
        routing(p0 + 1);
    }
}

// ---------------------------------------------------------------------------
// [pixel][boc] -> [boc][pixel] tiled transpose (fallback path only)
// ---------------------------------------------------------------------------
__global__ void transpose_kernel(const float* __restrict__ vtmp,
                                 float* __restrict__ out)
{
    __shared__ float tile[32][33];
    const int bp = blockIdx.x;
    const int bc = blockIdx.y;
    const int p0 = bp * 32, c0 = bc * 32;
    const int tx = threadIdx.x & 31, ty = threadIdx.x >> 5;

    for (int r = ty; r < 32; r += 8) {
        const int p = p0 + r;
        tile[r][tx] = (p < NPIX) ? vtmp[(size_t)p * 2048 + c0 + tx] : 0.f;
    }
    __syncthreads();
    for (int r = ty; r < 32; r += 8) {
        const int c = c0 + r;
        const int p = p0 + tx;
        if (p < NPIX) out[(size_t)c * NPIX + p] = tile[tx][r];
    }
}

// ---------------------------------------------------------------------------
// Round-1 fp32 fallback (proven correct) — used only if ws too small
// ---------------------------------------------------------------------------
__launch_bounds__(256, 2)
__global__ void capsconv_fp32(const float* __restrict__ x,
                              const float* __restrict__ Wc,
                              const float* __restrict__ bias,
                              float* __restrict__ outbuf,
                              const int direct_out)
{
    __shared__ float As[KC][BI];
    __shared__ float Bsh[KC][NOC];
    __shared__ float cij[64];
    __shared__ float bijs2[64];
    __shared__ float aTmp2[BB * 64];

    const int t  = threadIdx.x;
    const int tn = t & 15;
    const int tm = t >> 4;
    const int p  = blockIdx.x;
    const int px = p / OWH;
    const int py = p % OWH;
    const int row0 = 2 * px - 2;
    const int col0 = 2 * py - 2;
    const bool interior = (px >= 1 && px <= 63 && py >= 1 && py <= 63);

    float C[8][8];
#pragma unroll
    for (int r = 0; r < 8; ++r)
#pragma unroll
        for (int j = 0; j < 8; ++j) C[r][j] = 0.f;

    float areg[8][4];
    float breg[32];

    auto load_chunk = [&](int kc) {
#pragma unroll
        for (int g = 0; g < 8; ++g) {
            const int L    = g * 256 + t;
            const int bi   = L & 127;
            const int cikw = L >> 7;
            const int ci   = kc * 4 + (cikw >> 2);
            const int kw   = cikw & 3;
            const int row  = row0 + kw;
            const float* src = x + (((size_t)(bi * CIN + ci) * WH + row) * WH + col0);
            if (interior) {
                const float2 v01 = *(const float2*)(src);
                const float2 v23 = *(const float2*)(src + 2);
                areg[g][0] = v01.x; areg[g][1] = v01.y;
                areg[g][2] = v23.x; areg[g][3] = v23.y;
            } else {
#pragma unroll
                for (int kh = 0; kh < 4; ++kh) {
                    const int col = col0 + kh;
                    areg[g][kh] = (row >= 0 && row < WH && col >= 0 && col < WH)
                                      ? src[kh] : 0.f;
                }
            }
        }
        {
            const int oc  = t >> 1;
            const int kk0 = (t & 1) * 32;
            const float* wsrc = Wc + (size_t)oc * KTOT + kc * KC + kk0;
#pragma unroll
            for (int m = 0; m < 32; m += 4) {
                const float4 v = *(const float4*)(wsrc + m);
                breg[m] = v.x; breg[m+1] = v.y; breg[m+2] = v.z; breg[m+3] = v.w;
            }
        }
    };

    load_chunk(0);
    for (int kc = 0; kc < NCHUNK; ++kc) {
        __syncthreads();
#pragma unroll
        for (int g = 0; g < 8; ++g) {
            const int L    = g * 256 + t;
            const int bi   = L & 127;
            const int cikw = L >> 7;
            const int kkb  = cikw * 4;
#pragma unroll
            for (int kh = 0; kh < 4; ++kh) As[kkb + kh][bi] = areg[g][kh];
        }
        {
            const int oc  = t >> 1;
            const int kk0 = (t & 1) * 32;
#pragma unroll
            for (int m = 0; m < 32; ++m) Bsh[kk0 + m][oc] = breg[m];
        }
        __syncthreads();
        if (kc < NCHUNK - 1) load_chunk(kc + 1);
#pragma unroll 4
        for (int k = 0; k < KC; ++k) {
            float af[8], bf[8];
            *(float4*)(af)     = *(const float4*)&As[k][tm * 8];
            *(float4*)(af + 4) = *(const float4*)&As[k][tm * 8 + 4];
            *(float4*)(bf)     = *(const float4*)&Bsh[k][tn * 8];
            *(float4*)(bf + 4) = *(const float4*)&Bsh[k][tn * 8 + 4];
#pragma unroll
            for (int r = 0; r < 8; ++r)
#pragma unroll
                for (int j = 0; j < 8; ++j)
                    C[r][j] = fmaf(af[r], bf[j], C[r][j]);
        }
    }
#pragma unroll
    for (int j = 0; j < 8; ++j) {
        const float bj = bias[tn * 8 + j];
#pragma unroll
        for (int r = 0; r < 8; ++r) C[r][j] += bj;
    }

    const int o = tn >> 1;
    __syncthreads();
    if (t < 64) bijs2[t] = 0.f;

    float vout[8];
    for (int it = 0; it < 3; ++it) {
        __syncthreads();
        if (t < 8) {
            const int oo = t;
            float mx = -1e30f;
#pragma unroll
            for (int i = 0; i < 8; ++i) mx = fmaxf(mx, bijs2[i * 8 + oo]);
            float e[8]; float ssum = 0.f;
#pragma unroll
            for (int i = 0; i < 8; ++i) { e[i] = expf(bijs2[i * 8 + oo] - mx); ssum += e[i]; }
            const float inv = 1.f / ssum;
#pragma unroll
            for (int i = 0; i < 8; ++i) cij[i * 8 + oo] = e[i] * inv;
        }
        __syncthreads();
        float cf[8];
#pragma unroll
        for (int i = 0; i < 8; ++i) cf[i] = cij[i * 8 + o];
        float s[8];
#pragma unroll
        for (int j = 0; j < 8; ++j) {
            float acc = 0.f;
#pragma unroll
            for (int r = 0; r < 8; ++r) acc = fmaf(cf[r], C[r][j], acc);
            s[j] = acc;
        }
        float ssq = 0.f;
#pragma unroll
        for (int j = 0; j < 8; ++j) ssq = fmaf(s[j], s[j], ssq);
        ssq += __shfl_xor(ssq, 1);
        const float scale = ssq / ((1.f + ssq) * sqrtf(ssq));
        if (it == 2) {
#pragma unroll
            for (int j = 0; j < 8; ++j) vout[j] = s[j] * scale;
        } else {
            float ap[8];
#pragma unroll
            for (int r = 0; r < 8; ++r) {
                float acc = 0.f;
#pragma unroll
                for (int j = 0; j < 8; ++j) acc = fmaf(C[r][j], s[j] * scale, acc);
                ap[r] = acc;
            }
#pragma unroll
            for (int r = 0; r < 8; ++r) ap[r] += __shfl_xor(ap[r], 1);
            if ((tn & 1) == 0) {
#pragma unroll
                for (int r = 0; r < 8; ++r) aTmp2[tm * 64 + r * 8 + o] = ap[r];
            }
            __syncthreads();
            if (t < 64) {
                float acc = 0.f;
#pragma unroll
                for (int b = 0; b < BB; ++b) acc += aTmp2[b * 64 + t];
                bijs2[t] += acc * (1.f / 16.f);
            }
        }
    }
    if (direct_out) {
#pragma unroll
        for (int j = 0; j < 8; ++j)
            outbuf[(size_t)(tm * NOC + tn * 8 + j) * NPIX + p] = vout[j];
    } else {
        float4* dst = (float4*)(outbuf + (size_t)p * 2048 + tm * NOC + tn * 8);
        dst[0] = make_float4(vout[0], vout[1], vout[2], vout[3]);
        dst[1] = make_float4(vout[4], vout[5], vout[6], vout[7]);
    }
}

extern "C" void kernel_launch(void* const* d_in, const int* in_sizes, int n_in,
                              void* d_out, int out_size, void* d_ws, size_t ws_size,
                              hipStream_t stream)
{
    const float* x    = (const float*)d_in[0];
    const float* Wc   = (const float*)d_in[1];
    const float* bias = (const float*)d_in[2];
    float* out        = (float*)d_out;

    const size_t VT_BYTES = (size_t)NPIX * 2048 * sizeof(float);   // 34,611,200
    const size_t WB_OFF   = VT_BYTES;
    const size_t XB_OFF   = WB_OFF + 65536;
    const size_t TOTAL    = XB_OFF + (size_t)BI * CIN * WH * WH * 2;  // 101,785,600

    if (ws_size >= TOTAL) {
        ushortT* Wbf  = (ushortT*)((char*)d_ws + WB_OFF);
        ushortT* xbfT = (ushortT*)((char*)d_ws + XB_OFF);

        cvtT_kernel<<<S_TOTAL / 64, 256, 0, stream>>>(x, xbfT);
        prep_w_kernel<<<128, 256, 0, stream>>>(Wc, Wbf);
        capsconv_mfma<<<265 * 8, 512, 0, stream>>>(xbfT, Wbf, bias, out, 1);
    } else if (ws_size >= VT_BYTES) {
        float* vtmp = (float*)d_ws;
        capsconv_fp32<<<NPIX, 256, 0, stream>>>(x, Wc, bias, vtmp, 0);
        dim3 g((NPIX + 31) / 32, 2048 / 32);
        transpose_kernel<<<g, 256, 0, stream>>>(vtmp, out);
    } else {
        capsconv_fp32<<<NPIX, 256, 0, stream>>>(x, Wc, bias, out, 1);
    }
}

// Round 8
// 425.025 us; speedup vs baseline: 1.8974x; 1.8974x over previous
//
#include <hip/hip_runtime.h>
#include <math.h>

// Problem constants
#define BB   16      // batch
#define IC   8       // in capsules
#define BI   128     // BB*IC
#define CIN  16      // conv in channels
#define WH   128     // input spatial
#define OWH  65      // output spatial (stride 2, pad 2, k 4)
#define NPIX (OWH*OWH)   // 4225
#define OC   8       // out capsules
#define COUT 16      // out channel per capsule
#define NOC  128     // OC*Cout
#define KTOT 256     // CIN*4*4
#define KC   64      // (fp32 fallback chunk)
#define NCHUNK 4
#define S_TOTAL (CIN*WH*WH)   // 262144 (per-bi s = (ci,row,col) extent)

// MFMA kernel: K chunked by 32 (one mfma-K per chunk), 8 chunks
#define NCHM 8

typedef unsigned short ushortT;
typedef __bf16 bf16x8 __attribute__((ext_vector_type(8)));
typedef float  f32x4  __attribute__((ext_vector_type(4)));

__device__ __forceinline__ ushortT f2bf(float f) {
    unsigned u = __float_as_uint(f);
    unsigned r = (u + 0x7fffu + ((u >> 16) & 1u)) >> 16;
    return (ushortT)r;
}

// DPP lane move within 16-lane rows (rows == our quads): VALU pipe, no LDS.
// 0xB1 = quad_perm[1,0,3,2] (xor1), 0x4E = quad_perm[2,3,0,1] (xor2),
// 0x124 = row_ror:4, 0x128 = row_ror:8 (rotation all-reduce over {+0,+4,+8,+12}).
template <int CTRL>
__device__ __forceinline__ float dppMov(float x) {
    return __int_as_float(__builtin_amdgcn_update_dpp(
        0, __float_as_int(x), CTRL, 0xF, 0xF, true));
}

// LDS-only barrier: orders LDS (lgkmcnt(0)) but does NOT drain vmcnt ->
// global prefetches/stores ride across (T4). sched_barrier per rule #18.
#define LDS_BARRIER() do {                                    \
    asm volatile("s_waitcnt lgkmcnt(0)" ::: "memory");        \
    __builtin_amdgcn_s_barrier();                             \
    __builtin_amdgcn_sched_barrier(0);                        \
} while (0)

// ---------------------------------------------------------------------------
// Pre-pass 1: x fp32 [bi][ci][row][col] -> bf16 TRANSPOSED xbfT[s][bi],
// s = (ci*WH+row)*WH+col (bi innermost => GEMM A-staging is coalesced).
// LDS-tiled: block = 64 consecutive s x all 128 bi.
// ---------------------------------------------------------------------------
__global__ void cvtT_kernel(const float* __restrict__ x,
                            ushortT* __restrict__ xbfT)
{
    __shared__ ushortT tile[64 * 136];   // [sIdx][bi], stride 136, XOR-swizzled
    const int t  = threadIdx.x;          // 0..255
    const int s0 = blockIdx.x * 64;      // 4096 blocks

    // load: 2048 float4 (128 bi x 16 s-quads); 8 per thread
#pragma unroll
    for (int k = 0; k < 8; ++k) {
        const int j  = t + k * 256;
        const int bi = j >> 4, s4 = j & 15;
        const float4 v = *(const float4*)(x + (size_t)bi * S_TOTAL + s0 + s4 * 4);
        const int si = s4 * 4;
        tile[(si    ) * 136 + (bi ^ (((si    ) & 15) << 3))] = f2bf(v.x);
        tile[(si + 1) * 136 + (bi ^ (((si + 1) & 15) << 3))] = f2bf(v.y);
        tile[(si + 2) * 136 + (bi ^ (((si + 2) & 15) << 3))] = f2bf(v.z);
        tile[(si + 3) * 136 + (bi ^ (((si + 3) & 15) << 3))] = f2bf(v.w);
    }
    __syncthreads();
    // store: 1024 x 16B (64 s x 16 bi-octets); 4 per thread, fully coalesced
#pragma unroll
    for (int k = 0; k < 4; ++k) {
        const int j  = t + k * 256;
        const int sI = j >> 4, g = j & 15;
        const uint4 val = *(const uint4*)&tile[sI * 136 + ((g ^ (sI & 15)) << 3)];
        *(uint4*)(xbfT + (size_t)(s0 + sI) * 128 + g * 8) = val;
    }
}

// ---------------------------------------------------------------------------
// Pre-pass 2: W fp32 [oc][k] -> bf16 prepacked fragment image:
//   Wbf[(kpg*128+oc)*8 + j]   (k = kpg*8 + j, kpg = 0..31)
// ---------------------------------------------------------------------------
__global__ void prep_w_kernel(const float* __restrict__ W,
                              ushortT* __restrict__ Wbf)
{
    int idx = blockIdx.x * 256 + threadIdx.x;   // 32768 total
    int oc = idx >> 8, k = idx & 255;
    int kpg = k >> 3, j = k & 7;
    Wbf[((size_t)kpg * 128 + oc) * 8 + j] = f2bf(W[idx]);
}

// ---------------------------------------------------------------------------
// Fused MFMA kernel, 512 threads (8 waves). Wave w owns a 64x32 C quadrant:
// rows [64*(w>>2), +64) x cols [32*(w&3), +32) as 4x2 tiles of 16x16.
//
// v9 = v8 structure (2-pixel pipeline, proven correct on HW) with the
// register budget RESTORED: __launch_bounds__(512,4) (v7's proven setting).
// v8's (512,8) forced a 32-VGPR allocation -> wholesale scratch spill
// (WRITE_SIZE 37MB -> 1.3GB). Single-variable fix.
//   pre: chunks 0-2 in regs (aP0-2); issue loads 3,4 (aRr0/1);
//        store 0-2 -> bufs 0-2; barrier.
//   kc=0..7: compute buf kc%3 (chunk kc);
//     kc=1: store ch3->buf0, load ch5->aP0
//     kc=2: store ch4->buf1, load ch6->aP1
//     kc=3: store ch5->buf2, load ch7->aP2
//     kc=4: store ch6->buf0;  kc=5: store ch7->buf1;  barrier each kc.
// pixel1's chunks 0-2 issued BEFORE pixel0's routing, ride across it
// (routing barriers are lgkm-only). p0/p1 windows overlap 50% -> L1/L2-hot.
// C/D: col=lane&15 -> oc-col c, row=4*quad+reg -> (b,i). direct_out write.
// ---------------------------------------------------------------------------
__launch_bounds__(512, 4)
__global__ void capsconv_mfma(const ushortT* __restrict__ xbfT,
                              const ushortT* __restrict__ Wbf,
                              const float* __restrict__ bias,
                              float* __restrict__ outbuf,
                              const int direct_out)
{
    __shared__ __align__(16) ushortT As[3][4 * 128 * 8];   // 3 x 8 KB ring
    __shared__ float cijs[64];       // [o][i]
    __shared__ float bijs[64];       // [o][i] (wave 0 only)
    __shared__ float aTmp[16 * 64];  // [b][o*8+i]

    const int t  = threadIdx.x;      // 0..511
    const int g8 = blockIdx.x;       // 0..2119
    const int strip = g8 & 7;
    const int jj2   = g8 >> 3;               // 0..264
    const int p0 = strip * 529 + 2 * jj2;    // this block: p0 and maybe p0+1
    if (p0 >= NPIX) return;
    const bool p1ok = (2 * jj2 + 1 <= 528) && (p0 + 1 < NPIX);

    const int w  = t >> 6;       // wave id 0..7
    const int ln = t & 63;
    const int q  = ln >> 4;      // quad
    const int cL = ln & 15;      // lane col (c within tile)
    const int h  = q & 1;        // i-half
    const int mrow_base = 64 * (w >> 2);   // 0 or 64
    const int ncol_base = 32 * (w & 3);    // 0,32,64,96

    f32x4 acc[4][2];

    // ---- A staging map (thread-invariant parts) ----
    const int g     = t & 15;        // bi octet
    const int sI    = t >> 4;        // 0..31
    const int colw  = sI & 3;
    const int rowl  = (sI >> 2) & 3;
    const int cih   = sI >> 4;       // 0..1
    // LDS dest (bytes within As[buf]); bits 4-6 of wbase are zero.
    const int kpg   = cih * 2 + (rowl >> 1);
    const int jj    = (rowl & 1) * 4 + colw;
    const int wbase = (kpg * 128 + g * 8) * 16 + jj * 2;
    const int gk7   = g & 7;

    // fragment read byte offsets (swizzled), chunk-invariant
    int aRd[4];
#pragma unroll
    for (int mt = 0; mt < 4; ++mt) {
        const int by = (q * 128 + mrow_base + mt * 16 + cL) * 16;
        aRd[mt] = by ^ (((by >> 7) & 7) << 4);
    }

    uint4 aP0, aP1, aP2;   // prefetch regs (chunks 0-2, then 5-7)
    uint4 aRr0, aRr1;      // chunks 3,4

    auto mkAddr = [&](int pp, size_t& aoff, bool& okp) {
        const int ppx = pp / OWH, ppy = pp % OWH;
        const int srow2 = 2 * ppx - 2 + rowl;
        const int scol2 = 2 * ppy - 2 + colw;
        okp = (srow2 >= 0 && srow2 < WH && scol2 >= 0 && scol2 < WH);
        aoff = okp ? ((size_t)((cih * WH + srow2) * WH + scol2) * 128 + g * 8) : 0;
    };
    auto loadAx = [&](uint4& r, int kc, size_t aoff, bool okp) {
        r = make_uint4(0u, 0u, 0u, 0u);
        if (okp) r = *(const uint4*)(xbfT + aoff + (size_t)kc * (2 * WH * WH * 128));
    };
    auto storeA = [&](int buf, const uint4& r) {
        char* ab = (char*)&As[buf][0];
        const ushortT* av = (const ushortT*)&r;
#pragma unroll
        for (int c = 0; c < 8; ++c)
            *(ushortT*)(ab + wbase + ((c ^ gk7) << 4)) = av[c];
    };
    auto prefetch3 = [&](size_t aoff, bool okp) {
        loadAx(aP0, 0, aoff, okp);
        loadAx(aP1, 1, aoff, okp);
        loadAx(aP2, 2, aoff, okp);
    };

    auto gemm = [&](size_t aoff, bool okp) {
#pragma unroll
        for (int mt = 0; mt < 4; ++mt)
#pragma unroll
            for (int nt = 0; nt < 2; ++nt) acc[mt][nt] = (f32x4){0.f, 0.f, 0.f, 0.f};

        loadAx(aRr0, 3, aoff, okp);
        loadAx(aRr1, 4, aoff, okp);
        storeA(0, aP0);            // counted vmcnt waits land here
        storeA(1, aP1);
        storeA(2, aP2);
        LDS_BARRIER();

#pragma unroll
        for (int kc = 0; kc < NCHM; ++kc) {
            {
                const char* abase = (const char*)&As[kc % 3][0];
                bf16x8 af[4], bfr[2];
#pragma unroll
                for (int mt = 0; mt < 4; ++mt)
                    af[mt] = *(const bf16x8*)(abase + aRd[mt]);
                // B direct from global (L2-hot, no barrier dependency)
                const ushortT* bsrc = Wbf + kc * 4096 + (q * 128 + ncol_base + cL) * 8;
                bfr[0] = *(const bf16x8*)(bsrc);
                bfr[1] = *(const bf16x8*)(bsrc + 128);
#pragma unroll
                for (int mt = 0; mt < 4; ++mt)
#pragma unroll
                    for (int nt = 0; nt < 2; ++nt)
                        acc[mt][nt] = __builtin_amdgcn_mfma_f32_16x16x32_bf16(
                            af[mt], bfr[nt], acc[mt][nt], 0, 0, 0);
            }
            if (kc == 1)      { storeA(0, aRr0); loadAx(aP0, 5, aoff, okp); }
            else if (kc == 2) { storeA(1, aRr1); loadAx(aP1, 6, aoff, okp); }
            else if (kc == 3) { storeA(2, aP0);  loadAx(aP2, 7, aoff, okp); }
            else if (kc == 4) { storeA(0, aP1); }
            else if (kc == 5) { storeA(1, aP2); }
            LDS_BARRIER();
        }

        // bias epilogue
#pragma unroll
        for (int nt = 0; nt < 2; ++nt) {
            const float bv = bias[ncol_base + nt * 16 + cL];
#pragma unroll
            for (int mt = 0; mt < 4; ++mt) acc[mt][nt] += bv;
        }
    };

    // ---------------- dynamic routing (3 iters) ----------------
    auto routing = [&](int p) {
        for (int it = 0; it < 3; ++it) {
            float4 cf4[2];
            if (it == 0) {
#pragma unroll
                for (int nt = 0; nt < 2; ++nt)
                    cf4[nt] = make_float4(0.125f, 0.125f, 0.125f, 0.125f);
            } else {
#pragma unroll
                for (int nt = 0; nt < 2; ++nt)
                    cf4[nt] = *(const float4*)&cijs[(2 * (w & 3) + nt) * 8 + 4 * h];
            }

#pragma unroll
            for (int mt = 0; mt < 4; ++mt) {
                const int b = 8 * (w >> 2) + 2 * mt + (q >> 1);
#pragma unroll
                for (int nt = 0; nt < 2; ++nt) {
                    const int o = 2 * (w & 3) + nt;
                    const float4 cf = cf4[nt];
                    float sp = cf.x * acc[mt][nt][0] + cf.y * acc[mt][nt][1]
                             + cf.z * acc[mt][nt][2] + cf.w * acc[mt][nt][3];
                    float s = sp + __shfl_xor(sp, 16);
                    // ssq over the 16 cL lanes (DPP, VALU-only)
                    float ssq = s * s;
                    ssq += dppMov<0xB1>(ssq);
                    ssq += dppMov<0x4E>(ssq);
                    ssq += dppMov<0x124>(ssq);
                    ssq += dppMov<0x128>(ssq);
                    const float scale = sqrtf(ssq) * __builtin_amdgcn_rcpf(1.f + ssq);
                    const float vj = s * scale;

                    if (it == 2) {
                        if (q == 0 || q == 2) {
                            if (direct_out)
                                outbuf[(size_t)(b * NOC + o * 16 + cL) * NPIX + p] = vj;
                            else
                                outbuf[(size_t)p * 2048 + b * NOC + o * 16 + cL] = vj;
                        }
                    } else {
                        // fold: rows -> lanes; lane cL ends with row (cL&3)
                        f32x4 ap = acc[mt][nt] * vj;
                        const bool k1 = (cL & 1) != 0;
                        float e0 = k1 ? ap[1] : ap[0];
                        float o0 = k1 ? ap[0] : ap[1];
                        float e1 = k1 ? ap[3] : ap[2];
                        float o1 = k1 ? ap[2] : ap[3];
                        e0 += dppMov<0xB1>(o0);
                        e1 += dppMov<0xB1>(o1);
                        const bool k2 = (cL & 2) != 0;
                        float f0 = k2 ? e1 : e0;
                        float f1 = k2 ? e0 : e1;
                        f0 += dppMov<0x4E>(f1);
                        f0 += dppMov<0x124>(f0);
                        f0 += dppMov<0x128>(f0);
                        if (cL < 4)
                            aTmp[b * 64 + o * 8 + 4 * h + cL] = f0;
                    }
                }
            }
            if (it < 2) {
                LDS_BARRIER();   // aTmp writes visible (lgkm-only: no vmem deps)
                if (t < 64) {
                    float sum = 0.f;
#pragma unroll
                    for (int b = 0; b < BB; ++b) sum += aTmp[b * 64 + t];
                    float bij = (it == 0 ? 0.f : bijs[t]) + sum * (1.f / 16.f);
                    bijs[t] = bij;
                    float mx = bij;
                    mx = fmaxf(mx, __shfl_xor(mx, 1));
                    mx = fmaxf(mx, __shfl_xor(mx, 2));
                    mx = fmaxf(mx, __shfl_xor(mx, 4));
                    float e = __expf(bij - mx);
                    float se = e;
                    se += __shfl_xor(se, 1);
                    se += __shfl_xor(se, 2);
                    se += __shfl_xor(se, 4);
                    cijs[t] = e * __builtin_amdgcn_rcpf(se);
                }
                LDS_BARRIER();
            }
        }
    };

    // ---------------- 2-pixel pipeline ----------------
    size_t aoff0s, aoff1s;
    bool ok0, ok1;
    mkAddr(p0, aoff0s, ok0);

    prefetch3(aoff0s, ok0);          // pixel0 chunks 0-2 (cold)
    gemm(aoff0s, ok0);
    if (p1ok) {
        mkAddr(p0 + 1, aoff1s, ok1);
        prefetch3(aoff1s, ok1);      // pixel1 chunks 0-2: in flight across routing
    }
    routing(p0);
    if (p1ok) {
        gemm(aoff1s, ok1);
        routing(p0 + 1);
    }
}

// ---------------------------------------------------------------------------
// [pixel][boc] -> [boc][pixel] tiled transpose (fallback path only)
// ---------------------------------------------------------------------------
__global__ void transpose_kernel(const float* __restrict__ vtmp,
                                 float* __restrict__ out)
{
    __shared__ float tile[32][33];
    const int bp = blockIdx.x;
    const int bc = blockIdx.y;
    const int p0 = bp * 32, c0 = bc * 32;
    const int tx = threadIdx.x & 31, ty = threadIdx.x >> 5;

    for (int r = ty; r < 32; r += 8) {
        const int p = p0 + r;
        tile[r][tx] = (p < NPIX) ? vtmp[(size_t)p * 2048 + c0 + tx] : 0.f;
    }
    __syncthreads();
    for (int r = ty; r < 32; r += 8) {
        const int c = c0 + r;
        const int p = p0 + tx;
        if (p < NPIX) out[(size_t)c * NPIX + p] = tile[tx][r];
    }
}

// ---------------------------------------------------------------------------
// Round-1 fp32 fallback (proven correct) — used only if ws too small
// ---------------------------------------------------------------------------
__launch_bounds__(256, 2)
__global__ void capsconv_fp32(const float* __restrict__ x,
                              const float* __restrict__ Wc,
                              const float* __restrict__ bias,
                              float* __restrict__ outbuf,
                              const int direct_out)
{
    __shared__ float As[KC][BI];
    __shared__ float Bsh[KC][NOC];
    __shared__ float cij[64];
    __shared__ float bijs2[64];
    __shared__ float aTmp2[BB * 64];

    const int t  = threadIdx.x;
    const int tn = t & 15;
    const int tm = t >> 4;
    const int p  = blockIdx.x;
    const int px = p / OWH;
    const int py = p % OWH;
    const int row0 = 2 * px - 2;
    const int col0 = 2 * py - 2;
    const bool interior = (px >= 1 && px <= 63 && py >= 1 && py <= 63);

    float C[8][8];
#pragma unroll
    for (int r = 0; r < 8; ++r)
#pragma unroll
        for (int j = 0; j < 8; ++j) C[r][j] = 0.f;

    float areg[8][4];
    float breg[32];

    auto load_chunk = [&](int kc) {
#pragma unroll
        for (int g = 0; g < 8; ++g) {
            const int L    = g * 256 + t;
            const int bi   = L & 127;
            const int cikw = L >> 7;
            const int ci   = kc * 4 + (cikw >> 2);
            const int kw   = cikw & 3;
            const int row  = row0 + kw;
            const float* src = x + (((size_t)(bi * CIN + ci) * WH + row) * WH + col0);
            if (interior) {
                const float2 v01 = *(const float2*)(src);
                const float2 v23 = *(const float2*)(src + 2);
                areg[g][0] = v01.x; areg[g][1] = v01.y;
                areg[g][2] = v23.x; areg[g][3] = v23.y;
            } else {
#pragma unroll
                for (int kh = 0; kh < 4; ++kh) {
                    const int col = col0 + kh;
                    areg[g][kh] = (row >= 0 && row < WH && col >= 0 && col < WH)
                                      ? src[kh] : 0.f;
                }
            }
        }
        {
            const int oc  = t >> 1;
            const int kk0 = (t & 1) * 32;
            const float* wsrc = Wc + (size_t)oc * KTOT + kc * KC + kk0;
#pragma unroll
            for (int m = 0; m < 32; m += 4) {
                const float4 v = *(const float4*)(wsrc + m);
                breg[m] = v.x; breg[m+1] = v.y; breg[m+2] = v.z; breg[m+3] = v.w;
            }
        }
    };

    load_chunk(0);
    for (int kc = 0; kc < NCHUNK; ++kc) {
        __syncthreads();
#pragma unroll
        for (int g = 0; g < 8; ++g) {
            const int L    = g * 256 + t;
            const int bi   = L & 127;
            const int cikw = L >> 7;
            const int kkb  = cikw * 4;
#pragma unroll
            for (int kh = 0; kh < 4; ++kh) As[kkb + kh][bi] = areg[g][kh];
        }
        {
            const int oc  = t >> 1;
            const int kk0 = (t & 1) * 32;
#pragma unroll
            for (int m = 0; m < 32; ++m) Bsh[kk0 + m][oc] = breg[m];
        }
        __syncthreads();
        if (kc < NCHUNK - 1) load_chunk(kc + 1);
#pragma unroll 4
        for (int k = 0; k < KC; ++k) {
            float af[8], bf[8];
            *(float4*)(af)     = *(const float4*)&As[k][tm * 8];
            *(float4*)(af + 4) = *(const float4*)&As[k][tm * 8 + 4];
            *(float4*)(bf)     = *(const float4*)&Bsh[k][tn * 8];
            *(float4*)(bf + 4) = *(const float4*)&Bsh[k][tn * 8 + 4];
#pragma unroll
            for (int r = 0; r < 8; ++r)
#pragma unroll
                for (int j = 0; j < 8; ++j)
                    C[r][j] = fmaf(af[r], bf[j], C[r][j]);
        }
    }
#pragma unroll
    for (int j = 0; j < 8; ++j) {
        const float bj = bias[tn * 8 + j];
#pragma unroll
        for (int r = 0; r < 8; ++r) C[r][j] += bj;
    }

    const int o = tn >> 1;
    __syncthreads();
    if (t < 64) bijs2[t] = 0.f;

    float vout[8];
    for (int it = 0; it < 3; ++it) {
        __syncthreads();
        if (t < 8) {
            const int oo = t;
            float mx = -1e30f;
#pragma unroll
            for (int i = 0; i < 8; ++i) mx = fmaxf(mx, bijs2[i * 8 + oo]);
            float e[8]; float ssum = 0.f;
#pragma unroll
            for (int i = 0; i < 8; ++i) { e[i] = expf(bijs2[i * 8 + oo] - mx); ssum += e[i]; }
            const float inv = 1.f / ssum;
#pragma unroll
            for (int i = 0; i < 8; ++i) cij[i * 8 + oo] = e[i] * inv;
        }
        __syncthreads();
        float cf[8];
#pragma unroll
        for (int i = 0; i < 8; ++i) cf[i] = cij[i * 8 + o];
        float s[8];
#pragma unroll
        for (int j = 0; j < 8; ++j) {
            float acc = 0.f;
#pragma unroll
            for (int r = 0; r < 8; ++r) acc = fmaf(cf[r], C[r][j], acc);
            s[j] = acc;
        }
        float ssq = 0.f;
#pragma unroll
        for (int j = 0; j < 8; ++j) ssq = fmaf(s[j], s[j], ssq);
        ssq += __shfl_xor(ssq, 1);
        const float scale = ssq / ((1.f + ssq) * sqrtf(ssq));
        if (it == 2) {
#pragma unroll
            for (int j = 0; j < 8; ++j) vout[j] = s[j] * scale;
        } else {
            float ap[8];
#pragma unroll
            for (int r = 0; r < 8; ++r) {
                float acc = 0.f;
#pragma unroll
                for (int j = 0; j < 8; ++j) acc = fmaf(C[r][j], s[j] * scale, acc);
                ap[r] = acc;
            }
#pragma unroll
            for (int r = 0; r < 8; ++r) ap[r] += __shfl_xor(ap[r], 1);
            if ((tn & 1) == 0) {
#pragma unroll
                for (int r = 0; r < 8; ++r) aTmp2[tm * 64 + r * 8 + o] = ap[r];
            }
            __syncthreads();
            if (t < 64) {
                float acc = 0.f;
#pragma unroll
                for (int b = 0; b < BB; ++b) acc += aTmp2[b * 64 + t];
                bijs2[t] += acc * (1.f / 16.f);
            }
        }
    }
    if (direct_out) {
#pragma unroll
        for (int j = 0; j < 8; ++j)
            outbuf[(size_t)(tm * NOC + tn * 8 + j) * NPIX + p] = vout[j];
    } else {
        float4* dst = (float4*)(outbuf + (size_t)p * 2048 + tm * NOC + tn * 8);
        dst[0] = make_float4(vout[0], vout[1], vout[2], vout[3]);
        dst[1] = make_float4(vout[4], vout[5], vout[6], vout[7]);
    }
}

extern "C" void kernel_launch(void* const* d_in, const int* in_sizes, int n_in,
                              void* d_out, int out_size, void* d_ws, size_t ws_size,
                              hipStream_t stream)
{
    const float* x    = (const float*)d_in[0];
    const float* Wc   = (const float*)d_in[1];
    const float* bias = (const float*)d_in[2];
    float* out        = (float*)d_out;

    const size_t VT_BYTES = (size_t)NPIX * 2048 * sizeof(float);   // 34,611,200
    const size_t WB_OFF   = VT_BYTES;
    const size_t XB_OFF   = WB_OFF + 65536;
    const size_t TOTAL    = XB_OFF + (size_t)BI * CIN * WH * WH * 2;  // 101,785,600

    if (ws_size >= TOTAL) {
        ushortT* Wbf  = (ushortT*)((char*)d_ws + WB_OFF);
        ushortT* xbfT = (ushortT*)((char*)d_ws + XB_OFF);

        cvtT_kernel<<<S_TOTAL / 64, 256, 0, stream>>>(x, xbfT);
        prep_w_kernel<<<128, 256, 0, stream>>>(Wc, Wbf);
        capsconv_mfma<<<265 * 8, 512, 0, stream>>>(xbfT, Wbf, bias, out, 1);
    } else if (ws_size >= VT_BYTES) {
        float* vtmp = (float*)d_ws;
        capsconv_fp32<<<NPIX, 256, 0, stream>>>(x, Wc, bias, vtmp, 0);
        dim3 g((NPIX + 31) / 32, 2048 / 32);
        transpose_kernel<<<g, 256, 0, stream>>>(vtmp, out);
    } else {
        capsconv_fp32<<<NPIX, 256, 0, stream>>>(x, Wc, bias, out, 1);
    }
}

// Round 9
// 424.600 us; speedup vs baseline: 1.8993x; 1.0010x over previous
//
#include <hip/hip_runtime.h>
#include <math.h>

// Problem constants
#define BB   16      // batch
#define IC   8       // in capsules
#define BI   128     // BB*IC
#define CIN  16      // conv in channels
#define WH   128     // input spatial
#define OWH  65      // output spatial (stride 2, pad 2, k 4)
#define NPIX (OWH*OWH)   // 4225
#define OC   8       // out capsules
#define COUT 16      // out channel per capsule
#define NOC  128     // OC*Cout
#define KTOT 256     // CIN*4*4
#define KC   64      // (fp32 fallback chunk)
#define NCHUNK 4
#define S_TOTAL (CIN*WH*WH)   // 262144 (per-bi s = (ci,row,col) extent)

// MFMA kernel: K chunked by 32 (one mfma-K per chunk), 8 chunks
#define NCHM 8

typedef unsigned short ushortT;
typedef __bf16 bf16x8 __attribute__((ext_vector_type(8)));
typedef float  f32x4  __attribute__((ext_vector_type(4)));

__device__ __forceinline__ ushortT f2bf(float f) {
    unsigned u = __float_as_uint(f);
    unsigned r = (u + 0x7fffu + ((u >> 16) & 1u)) >> 16;
    return (ushortT)r;
}

// DPP lane move within 16-lane rows (rows == our quads): VALU pipe, no LDS.
// 0xB1 = quad_perm[1,0,3,2] (xor1), 0x4E = quad_perm[2,3,0,1] (xor2),
// 0x124 = row_ror:4, 0x128 = row_ror:8 (rotation all-reduce over {+0,+4,+8,+12}).
template <int CTRL>
__device__ __forceinline__ float dppMov(float x) {
    return __int_as_float(__builtin_amdgcn_update_dpp(
        0, __float_as_int(x), CTRL, 0xF, 0xF, true));
}

// LDS-only barrier: orders LDS (lgkmcnt(0)) but does NOT drain vmcnt ->
// global prefetches/stores ride across (T4). sched_barrier per rule #18.
#define LDS_BARRIER() do {                                    \
    asm volatile("s_waitcnt lgkmcnt(0)" ::: "memory");        \
    __builtin_amdgcn_s_barrier();                             \
    __builtin_amdgcn_sched_barrier(0);                        \
} while (0)

// ---------------------------------------------------------------------------
// Pre-pass 1: x fp32 [bi][ci][row][col] -> bf16 TRANSPOSED xbfT[s][bi],
// s = (ci*WH+row)*WH+col (bi innermost => GEMM A-staging is coalesced).
// LDS-tiled: block = 64 consecutive s x all 128 bi.
// ---------------------------------------------------------------------------
__global__ void cvtT_kernel(const float* __restrict__ x,
                            ushortT* __restrict__ xbfT)
{
    __shared__ ushortT tile[64 * 136];   // [sIdx][bi], stride 136, XOR-swizzled
    const int t  = threadIdx.x;          // 0..255
    const int s0 = blockIdx.x * 64;      // 4096 blocks

    // load: 2048 float4 (128 bi x 16 s-quads); 8 per thread
#pragma unroll
    for (int k = 0; k < 8; ++k) {
        const int j  = t + k * 256;
        const int bi = j >> 4, s4 = j & 15;
        const float4 v = *(const float4*)(x + (size_t)bi * S_TOTAL + s0 + s4 * 4);
        const int si = s4 * 4;
        tile[(si    ) * 136 + (bi ^ (((si    ) & 15) << 3))] = f2bf(v.x);
        tile[(si + 1) * 136 + (bi ^ (((si + 1) & 15) << 3))] = f2bf(v.y);
        tile[(si + 2) * 136 + (bi ^ (((si + 2) & 15) << 3))] = f2bf(v.z);
        tile[(si + 3) * 136 + (bi ^ (((si + 3) & 15) << 3))] = f2bf(v.w);
    }
    __syncthreads();
    // store: 1024 x 16B (64 s x 16 bi-octets); 4 per thread, fully coalesced
#pragma unroll
    for (int k = 0; k < 4; ++k) {
        const int j  = t + k * 256;
        const int sI = j >> 4, g = j & 15;
        const uint4 val = *(const uint4*)&tile[sI * 136 + ((g ^ (sI & 15)) << 3)];
        *(uint4*)(xbfT + (size_t)(s0 + sI) * 128 + g * 8) = val;
    }
}

// ---------------------------------------------------------------------------
// Pre-pass 2: W fp32 [oc][k] -> bf16 prepacked fragment image:
//   Wbf[(kpg*128+oc)*8 + j]   (k = kpg*8 + j, kpg = 0..31)
// ---------------------------------------------------------------------------
__global__ void prep_w_kernel(const float* __restrict__ W,
                              ushortT* __restrict__ Wbf)
{
    int idx = blockIdx.x * 256 + threadIdx.x;   // 32768 total
    int oc = idx >> 8, k = idx & 255;
    int kpg = k >> 3, j = k & 7;
    Wbf[((size_t)kpg * 128 + oc) * 8 + j] = f2bf(W[idx]);
}

// ---------------------------------------------------------------------------
// Fused MFMA kernel, 512 threads (8 waves). Wave w owns a 64x32 C quadrant:
// rows [64*(w>>2), +64) x cols [32*(w&3), +32) as 4x2 tiles of 16x16.
//
// v10 = v9 (2-pixel pipeline, proven correct on HW) with the launch bound's
// min-waves clause REMOVED. Empirical calibration on this kernel:
// arg2=8 -> 32-VGPR cap (v8, 1.3GB spill), arg2=4 -> 64-VGPR cap (v9,
// 500MB spill). Live state needs ~85-100 VGPR -> let the allocator take it
// (occupancy: 4 waves/SIMD, 2 blocks/CU; LDS allows 5 -> VGPR-bound, fine).
//   pre: chunks 0-2 in regs (aP0-2); issue loads 3,4 (aRr0/1);
//        store 0-2 -> bufs 0-2; barrier.
//   kc=0..7: compute buf kc%3 (chunk kc);
//     kc=1: store ch3->buf0, load ch5->aP0
//     kc=2: store ch4->buf1, load ch6->aP1
//     kc=3: store ch5->buf2, load ch7->aP2
//     kc=4: store ch6->buf0;  kc=5: store ch7->buf1;  barrier each kc.
// pixel1's chunks 0-2 issued BEFORE pixel0's routing, ride across it
// (routing barriers are lgkm-only). p0/p1 windows overlap 50% -> L1/L2-hot.
// C/D: col=lane&15 -> oc-col c, row=4*quad+reg -> (b,i). direct_out write.
// ---------------------------------------------------------------------------
__launch_bounds__(512)
__global__ void capsconv_mfma(const ushortT* __restrict__ xbfT,
                              const ushortT* __restrict__ Wbf,
                              const float* __restrict__ bias,
                              float* __restrict__ outbuf,
                              const int direct_out)
{
    __shared__ __align__(16) ushortT As[3][4 * 128 * 8];   // 3 x 8 KB ring
    __shared__ float cijs[64];       // [o][i]
    __shared__ float bijs[64];       // [o][i] (wave 0 only)
    __shared__ float aTmp[16 * 64];  // [b][o*8+i]

    const int t  = threadIdx.x;      // 0..511
    const int g8 = blockIdx.x;       // 0..2119
    const int strip = g8 & 7;
    const int jj2   = g8 >> 3;               // 0..264
    const int p0 = strip * 529 + 2 * jj2;    // this block: p0 and maybe p0+1
    if (p0 >= NPIX) return;
    const bool p1ok = (2 * jj2 + 1 <= 528) && (p0 + 1 < NPIX);

    const int w  = t >> 6;       // wave id 0..7
    const int ln = t & 63;
    const int q  = ln >> 4;      // quad
    const int cL = ln & 15;      // lane col (c within tile)
    const int h  = q & 1;        // i-half
    const int mrow_base = 64 * (w >> 2);   // 0 or 64
    const int ncol_base = 32 * (w & 3);    // 0,32,64,96

    f32x4 acc[4][2];

    // ---- A staging map (thread-invariant parts) ----
    const int g     = t & 15;        // bi octet
    const int sI    = t >> 4;        // 0..31
    const int colw  = sI & 3;
    const int rowl  = (sI >> 2) & 3;
    const int cih   = sI >> 4;       // 0..1
    // LDS dest (bytes within As[buf]); bits 4-6 of wbase are zero.
    const int kpg   = cih * 2 + (rowl >> 1);
    const int jj    = (rowl & 1) * 4 + colw;
    const int wbase = (kpg * 128 + g * 8) * 16 + jj * 2;
    const int gk7   = g & 7;

    // fragment read byte offsets (swizzled), chunk-invariant
    int aRd[4];
#pragma unroll
    for (int mt = 0; mt < 4; ++mt) {
        const int by = (q * 128 + mrow_base + mt * 16 + cL) * 16;
        aRd[mt] = by ^ (((by >> 7) & 7) << 4);
    }

    uint4 aP0, aP1, aP2;   // prefetch regs (chunks 0-2, then 5-7)
    uint4 aRr0, aRr1;      // chunks 3,4

    auto mkAddr = [&](int pp, size_t& aoff, bool& okp) {
        const int ppx = pp / OWH, ppy = pp % OWH;
        const int srow2 = 2 * ppx - 2 + rowl;
        const int scol2 = 2 * ppy - 2 + colw;
        okp = (srow2 >= 0 && srow2 < WH && scol2 >= 0 && scol2 < WH);
        aoff = okp ? ((size_t)((cih * WH + srow2) * WH + scol2) * 128 + g * 8) : 0;
    };
    auto loadAx = [&](uint4& r, int kc, size_t aoff, bool okp) {
        r = make_uint4(0u, 0u, 0u, 0u);
        if (okp) r = *(const uint4*)(xbfT + aoff + (size_t)kc * (2 * WH * WH * 128));
    };
    auto storeA = [&](int buf, const uint4& r) {
        char* ab = (char*)&As[buf][0];
        const ushortT* av = (const ushortT*)&r;
#pragma unroll
        for (int c = 0; c < 8; ++c)
            *(ushortT*)(ab + wbase + ((c ^ gk7) << 4)) = av[c];
    };
    auto prefetch3 = [&](size_t aoff, bool okp) {
        loadAx(aP0, 0, aoff, okp);
        loadAx(aP1, 1, aoff, okp);
        loadAx(aP2, 2, aoff, okp);
    };

    auto gemm = [&](size_t aoff, bool okp) {
#pragma unroll
        for (int mt = 0; mt < 4; ++mt)
#pragma unroll
            for (int nt = 0; nt < 2; ++nt) acc[mt][nt] = (f32x4){0.f, 0.f, 0.f, 0.f};

        loadAx(aRr0, 3, aoff, okp);
        loadAx(aRr1, 4, aoff, okp);
        storeA(0, aP0);            // counted vmcnt waits land here
        storeA(1, aP1);
        storeA(2, aP2);
        LDS_BARRIER();

#pragma unroll
        for (int kc = 0; kc < NCHM; ++kc) {
            {
                const char* abase = (const char*)&As[kc % 3][0];
                bf16x8 af[4], bfr[2];
#pragma unroll
                for (int mt = 0; mt < 4; ++mt)
                    af[mt] = *(const bf16x8*)(abase + aRd[mt]);
                // B direct from global (L2-hot, no barrier dependency)
                const ushortT* bsrc = Wbf + kc * 4096 + (q * 128 + ncol_base + cL) * 8;
                bfr[0] = *(const bf16x8*)(bsrc);
                bfr[1] = *(const bf16x8*)(bsrc + 128);
#pragma unroll
                for (int mt = 0; mt < 4; ++mt)
#pragma unroll
                    for (int nt = 0; nt < 2; ++nt)
                        acc[mt][nt] = __builtin_amdgcn_mfma_f32_16x16x32_bf16(
                            af[mt], bfr[nt], acc[mt][nt], 0, 0, 0);
            }
            if (kc == 1)      { storeA(0, aRr0); loadAx(aP0, 5, aoff, okp); }
            else if (kc == 2) { storeA(1, aRr1); loadAx(aP1, 6, aoff, okp); }
            else if (kc == 3) { storeA(2, aP0);  loadAx(aP2, 7, aoff, okp); }
            else if (kc == 4) { storeA(0, aP1); }
            else if (kc == 5) { storeA(1, aP2); }
            LDS_BARRIER();
        }

        // bias epilogue
#pragma unroll
        for (int nt = 0; nt < 2; ++nt) {
            const float bv = bias[ncol_base + nt * 16 + cL];
#pragma unroll
            for (int mt = 0; mt < 4; ++mt) acc[mt][nt] += bv;
        }
    };

    // ---------------- dynamic routing (3 iters) ----------------
    auto routing = [&](int p) {
        for (int it = 0; it < 3; ++it) {
            float4 cf4[2];
            if (it == 0) {
#pragma unroll
                for (int nt = 0; nt < 2; ++nt)
                    cf4[nt] = make_float4(0.125f, 0.125f, 0.125f, 0.125f);
            } else {
#pragma unroll
                for (int nt = 0; nt < 2; ++nt)
                    cf4[nt] = *(const float4*)&cijs[(2 * (w & 3) + nt) * 8 + 4 * h];
            }

#pragma unroll
            for (int mt = 0; mt < 4; ++mt) {
                const int b = 8 * (w >> 2) + 2 * mt + (q >> 1);
#pragma unroll
                for (int nt = 0; nt < 2; ++nt) {
                    const int o = 2 * (w & 3) + nt;
                    const float4 cf = cf4[nt];
                    float sp = cf.x * acc[mt][nt][0] + cf.y * acc[mt][nt][1]
                             + cf.z * acc[mt][nt][2] + cf.w * acc[mt][nt][3];
                    float s = sp + __shfl_xor(sp, 16);
                    // ssq over the 16 cL lanes (DPP, VALU-only)
                    float ssq = s * s;
                    ssq += dppMov<0xB1>(ssq);
                    ssq += dppMov<0x4E>(ssq);
                    ssq += dppMov<0x124>(ssq);
                    ssq += dppMov<0x128>(ssq);
                    const float scale = sqrtf(ssq) * __builtin_amdgcn_rcpf(1.f + ssq);
                    const float vj = s * scale;

                    if (it == 2) {
                        if (q == 0 || q == 2) {
                            if (direct_out)
                                outbuf[(size_t)(b * NOC + o * 16 + cL) * NPIX + p] = vj;
                            else
                                outbuf[(size_t)p * 2048 + b * NOC + o * 16 + cL] = vj;
                        }
                    } else {
                        // fold: rows -> lanes; lane cL ends with row (cL&3)
                        f32x4 ap = acc[mt][nt] * vj;
                        const bool k1 = (cL & 1) != 0;
                        float e0 = k1 ? ap[1] : ap[0];
                        float o0 = k1 ? ap[0] : ap[1];
                        float e1 = k1 ? ap[3] : ap[2];
                        float o1 = k1 ? ap[2] : ap[3];
                        e0 += dppMov<0xB1>(o0);
                        e1 += dppMov<0xB1>(o1);
                        const bool k2 = (cL & 2) != 0;
                        float f0 = k2 ? e1 : e0;
                        float f1 = k2 ? e0 : e1;
                        f0 += dppMov<0x4E>(f1);
                        f0 += dppMov<0x124>(f0);
                        f0 += dppMov<0x128>(f0);
                        if (cL < 4)
                            aTmp[b * 64 + o * 8 + 4 * h + cL] = f0;
                    }
                }
            }
            if (it < 2) {
                LDS_BARRIER();   // aTmp writes visible (lgkm-only: no vmem deps)
                if (t < 64) {
                    float sum = 0.f;
#pragma unroll
                    for (int b = 0; b < BB; ++b) sum += aTmp[b * 64 + t];
                    float bij = (it == 0 ? 0.f : bijs[t]) + sum * (1.f / 16.f);
                    bijs[t] = bij;
                    float mx = bij;
                    mx = fmaxf(mx, __shfl_xor(mx, 1));
                    mx = fmaxf(mx, __shfl_xor(mx, 2));
                    mx = fmaxf(mx, __shfl_xor(mx, 4));
                    float e = __expf(bij - mx);
                    float se = e;
                    se += __shfl_xor(se, 1);
                    se += __shfl_xor(se, 2);
                    se += __shfl_xor(se, 4);
                    cijs[t] = e * __builtin_amdgcn_rcpf(se);
                }
                LDS_BARRIER();
            }
        }
    };

    // ---------------- 2-pixel pipeline ----------------
    size_t aoff0s, aoff1s;
    bool ok0, ok1;
    mkAddr(p0, aoff0s, ok0);

    prefetch3(aoff0s, ok0);          // pixel0 chunks 0-2 (cold)
    gemm(aoff0s, ok0);
    if (p1ok) {
        mkAddr(p0 + 1, aoff1s, ok1);
        prefetch3(aoff1s, ok1);      // pixel1 chunks 0-2: in flight across routing
    }
    routing(p0);
    if (p1ok) {
        gemm(aoff1s, ok1);
        routing(p0 + 1);
    }
}

// ---------------------------------------------------------------------------
// [pixel][boc] -> [boc][pixel] tiled transpose (fallback path only)
// ---------------------------------------------------------------------------
__global__ void transpose_kernel(const float* __restrict__ vtmp,
                                 float* __restrict__ out)
{
    __shared__ float tile[32][33];
    const int bp = blockIdx.x;
    const int bc = blockIdx.y;
    const int p0 = bp * 32, c0 = bc * 32;
    const int tx = threadIdx.x & 31, ty = threadIdx.x >> 5;

    for (int r = ty; r < 32; r += 8) {
        const int p = p0 + r;
        tile[r][tx] = (p < NPIX) ? vtmp[(size_t)p * 2048 + c0 + tx] : 0.f;
    }
    __syncthreads();
    for (int r = ty; r < 32; r += 8) {
        const int c = c0 + r;
        const int p = p0 + tx;
        if (p < NPIX) out[(size_t)c * NPIX + p] = tile[tx][r];
    }
}

// ---------------------------------------------------------------------------
// Round-1 fp32 fallback (proven correct) — used only if ws too small
// ---------------------------------------------------------------------------
__launch_bounds__(256, 2)
__global__ void capsconv_fp32(const float* __restrict__ x,
                              const float* __restrict__ Wc,
                              const float* __restrict__ bias,
                              float* __restrict__ outbuf,
                              const int direct_out)
{
    __shared__ float As[KC][BI];
    __shared__ float Bsh[KC][NOC];
    __shared__ float cij[64];
    __shared__ float bijs2[64];
    __shared__ float aTmp2[BB * 64];

    const int t  = threadIdx.x;
    const int tn = t & 15;
    const int tm = t >> 4;
    const int p  = blockIdx.x;
    const int px = p / OWH;
    const int py = p % OWH;
    const int row0 = 2 * px - 2;
    const int col0 = 2 * py - 2;
    const bool interior = (px >= 1 && px <= 63 && py >= 1 && py <= 63);

    float C[8][8];
#pragma unroll
    for (int r = 0; r < 8; ++r)
#pragma unroll
        for (int j = 0; j < 8; ++j) C[r][j] = 0.f;

    float areg[8][4];
    float breg[32];

    auto load_chunk = [&](int kc) {
#pragma unroll
        for (int g = 0; g < 8; ++g) {
            const int L    = g * 256 + t;
            const int bi   = L & 127;
            const int cikw = L >> 7;
            const int ci   = kc * 4 + (cikw >> 2);
            const int kw   = cikw & 3;
            const int row  = row0 + kw;
            const float* src = x + (((size_t)(bi * CIN + ci) * WH + row) * WH + col0);
            if (interior) {
                const float2 v01 = *(const float2*)(src);
                const float2 v23 = *(const float2*)(src + 2);
                areg[g][0] = v01.x; areg[g][1] = v01.y;
                areg[g][2] = v23.x; areg[g][3] = v23.y;
            } else {
#pragma unroll
                for (int kh = 0; kh < 4; ++kh) {
                    const int col = col0 + kh;
                    areg[g][kh] = (row >= 0 && row < WH && col >= 0 && col < WH)
                                      ? src[kh] : 0.f;
                }
            }
        }
        {
            const int oc  = t >> 1;
            const int kk0 = (t & 1) * 32;
            const float* wsrc = Wc + (size_t)oc * KTOT + kc * KC + kk0;
#pragma unroll
            for (int m = 0; m < 32; m += 4) {
                const float4 v = *(const float4*)(wsrc + m);
                breg[m] = v.x; breg[m+1] = v.y; breg[m+2] = v.z; breg[m+3] = v.w;
            }
        }
    };

    load_chunk(0);
    for (int kc = 0; kc < NCHUNK; ++kc) {
        __syncthreads();
#pragma unroll
        for (int g = 0; g < 8; ++g) {
            const int L    = g * 256 + t;
            const int bi   = L & 127;
            const int cikw = L >> 7;
            const int kkb  = cikw * 4;
#pragma unroll
            for (int kh = 0; kh < 4; ++kh) As[kkb + kh][bi] = areg[g][kh];
        }
        {
            const int oc  = t >> 1;
            const int kk0 = (t & 1) * 32;
#pragma unroll
            for (int m = 0; m < 32; ++m) Bsh[kk0 + m][oc] = breg[m];
        }
        __syncthreads();
        if (kc < NCHUNK - 1) load_chunk(kc + 1);
#pragma unroll 4
        for (int k = 0; k < KC; ++k) {
            float af[8], bf[8];
            *(float4*)(af)     = *(const float4*)&As[k][tm * 8];
            *(float4*)(af + 4) = *(const float4*)&As[k][tm * 8 + 4];
            *(float4*)(bf)     = *(const float4*)&Bsh[k][tn * 8];
            *(float4*)(bf + 4) = *(const float4*)&Bsh[k][tn * 8 + 4];
#pragma unroll
            for (int r = 0; r < 8; ++r)
#pragma unroll
                for (int j = 0; j < 8; ++j)
                    C[r][j] = fmaf(af[r], bf[j], C[r][j]);
        }
    }
#pragma unroll
    for (int j = 0; j < 8; ++j) {
        const float bj = bias[tn * 8 + j];
#pragma unroll
        for (int r = 0; r < 8; ++r) C[r][j] += bj;
    }

    const int o = tn >> 1;
    __syncthreads();
    if (t < 64) bijs2[t] = 0.f;

    float vout[8];
    for (int it = 0; it < 3; ++it) {
        __syncthreads();
        if (t < 8) {
            const int oo = t;
            float mx = -1e30f;
#pragma unroll
            for (int i = 0; i < 8; ++i) mx = fmaxf(mx, bijs2[i * 8 + oo]);
            float e[8]; float ssum = 0.f;
#pragma unroll
            for (int i = 0; i < 8; ++i) { e[i] = expf(bijs2[i * 8 + oo] - mx); ssum += e[i]; }
            const float inv = 1.f / ssum;
#pragma unroll
            for (int i = 0; i < 8; ++i) cij[i * 8 + oo] = e[i] * inv;
        }
        __syncthreads();
        float cf[8];
#pragma unroll
        for (int i = 0; i < 8; ++i) cf[i] = cij[i * 8 + o];
        float s[8];
#pragma unroll
        for (int j = 0; j < 8; ++j) {
            float acc = 0.f;
#pragma unroll
            for (int r = 0; r < 8; ++r) acc = fmaf(cf[r], C[r][j], acc);
            s[j] = acc;
        }
        float ssq = 0.f;
#pragma unroll
        for (int j = 0; j < 8; ++j) ssq = fmaf(s[j], s[j], ssq);
        ssq += __shfl_xor(ssq, 1);
        const float scale = ssq / ((1.f + ssq) * sqrtf(ssq));
        if (it == 2) {
#pragma unroll
            for (int j = 0; j < 8; ++j) vout[j] = s[j] * scale;
        } else {
            float ap[8];
#pragma unroll
            for (int r = 0; r < 8; ++r) {
                float acc = 0.f;
#pragma unroll
                for (int j = 0; j < 8; ++j) acc = fmaf(C[r][j], s[j] * scale, acc);
                ap[r] = acc;
            }
#pragma unroll
            for (int r = 0; r < 8; ++r) ap[r] += __shfl_xor(ap[r], 1);
            if ((tn & 1) == 0) {
#pragma unroll
                for (int r = 0; r < 8; ++r) aTmp2[tm * 64 + r * 8 + o] = ap[r];
            }
            __syncthreads();
            if (t < 64) {
                float acc = 0.f;
#pragma unroll
                for (int b = 0; b < BB; ++b) acc += aTmp2[b * 64 + t];
                bijs2[t] += acc * (1.f / 16.f);
            }
        }
    }
    if (direct_out) {
#pragma unroll
        for (int j = 0; j < 8; ++j)
            outbuf[(size_t)(tm * NOC + tn * 8 + j) * NPIX + p] = vout[j];
    } else {
        float4* dst = (float4*)(outbuf + (size_t)p * 2048 + tm * NOC + tn * 8);
        dst[0] = make_float4(vout[0], vout[1], vout[2], vout[3]);
        dst[1] = make_float4(vout[4], vout[5], vout[6], vout[7]);
    }
}

extern "C" void kernel_launch(void* const* d_in, const int* in_sizes, int n_in,
                              void* d_out, int out_size, void* d_ws, size_t ws_size,
                              hipStream_t stream)
{
    const float* x    = (const float*)d_in[0];
    const float* Wc   = (const float*)d_in[1];
    const float* bias = (const float*)d_in[2];
    float* out        = (float*)d_out;

    const size_t VT_BYTES = (size_t)NPIX * 2048 * sizeof(float);   // 34,611,200
    const size_t WB_OFF   = VT_BYTES;
    const size_t XB_OFF   = WB_OFF + 65536;
    const size_t TOTAL    = XB_OFF + (size_t)BI * CIN * WH * WH * 2;  // 101,785,600

    if (ws_size >= TOTAL) {
        ushortT* Wbf  = (ushortT*)((char*)d_ws + WB_OFF);
        ushortT* xbfT = (ushortT*)((char*)d_ws + XB_OFF);

        cvtT_kernel<<<S_TOTAL / 64, 256, 0, stream>>>(x, xbfT);
        prep_w_kernel<<<128, 256, 0, stream>>>(Wc, Wbf);
        capsconv_mfma<<<265 * 8, 512, 0, stream>>>(xbfT, Wbf, bias, out, 1);
    } else if (ws_size >= VT_BYTES) {
        float* vtmp = (float*)d_ws;
        capsconv_fp32<<<NPIX, 256, 0, stream>>>(x, Wc, bias, vtmp, 0);
        dim3 g((NPIX + 31) / 32, 2048 / 32);
        transpose_kernel<<<g, 256, 0, stream>>>(vtmp, out);
    } else {
        capsconv_fp32<<<NPIX, 256, 0, stream>>>(x, Wc, bias, out, 1);
    }
}

// Round 10
// 343.700 us; speedup vs baseline: 2.3464x; 1.2354x over previous
//
#include <hip/hip_runtime.h>
#include <math.h>

// Problem constants
#define BB   16      // batch
#define IC   8       // in capsules
#define BI   128     // BB*IC
#define CIN  16      // conv in channels
#define WH   128     // input spatial
#define OWH  65      // output spatial (stride 2, pad 2, k 4)
#define NPIX (OWH*OWH)   // 4225
#define OC   8       // out capsules
#define COUT 16      // out channel per capsule
#define NOC  128     // OC*Cout
#define KTOT 256     // CIN*4*4
#define KC   64      // (fp32 fallback chunk)
#define NCHUNK 4
#define S_TOTAL (CIN*WH*WH)   // 262144 (per-bi s = (ci,row,col) extent)

// MFMA kernel: K chunked by 32 (one mfma-K per chunk), 8 chunks
#define NCHM 8

typedef unsigned short ushortT;
typedef __bf16 bf16x8 __attribute__((ext_vector_type(8)));
typedef float  f32x4  __attribute__((ext_vector_type(4)));

__device__ __forceinline__ ushortT f2bf(float f) {
    unsigned u = __float_as_uint(f);
    unsigned r = (u + 0x7fffu + ((u >> 16) & 1u)) >> 16;
    return (ushortT)r;
}

// DPP lane move within 16-lane rows (rows == our quads): VALU pipe, no LDS.
// 0xB1 = quad_perm[1,0,3,2] (xor1), 0x4E = quad_perm[2,3,0,1] (xor2),
// 0x124 = row_ror:4, 0x128 = row_ror:8 (rotation all-reduce over {+0,+4,+8,+12}).
template <int CTRL>
__device__ __forceinline__ float dppMov(float x) {
    return __int_as_float(__builtin_amdgcn_update_dpp(
        0, __float_as_int(x), CTRL, 0xF, 0xF, true));
}

// LDS-only barrier: orders LDS (lgkmcnt(0)) but does NOT drain vmcnt ->
// global prefetches ride across (T4). sched_barrier per rule #18.
#define LDS_BARRIER() do {                                    \
    asm volatile("s_waitcnt lgkmcnt(0)" ::: "memory");        \
    __builtin_amdgcn_s_barrier();                             \
    __builtin_amdgcn_sched_barrier(0);                        \
} while (0)

// ---------------------------------------------------------------------------
// Pre-pass 1: x fp32 [bi][ci][row][col] -> bf16 TRANSPOSED xbfT[s][bi],
// s = (ci*WH+row)*WH+col (bi innermost => GEMM A-staging is coalesced).
// LDS-tiled: block = 64 consecutive s x all 128 bi.
// ---------------------------------------------------------------------------
__global__ void cvtT_kernel(const float* __restrict__ x,
                            ushortT* __restrict__ xbfT)
{
    __shared__ ushortT tile[64 * 136];   // [sIdx][bi], stride 136, XOR-swizzled
    const int t  = threadIdx.x;          // 0..255
    const int s0 = blockIdx.x * 64;      // 4096 blocks

    // load: 2048 float4 (128 bi x 16 s-quads); 8 per thread
#pragma unroll
    for (int k = 0; k < 8; ++k) {
        const int j  = t + k * 256;
        const int bi = j >> 4, s4 = j & 15;
        const float4 v = *(const float4*)(x + (size_t)bi * S_TOTAL + s0 + s4 * 4);
        const int si = s4 * 4;
        tile[(si    ) * 136 + (bi ^ (((si    ) & 15) << 3))] = f2bf(v.x);
        tile[(si + 1) * 136 + (bi ^ (((si + 1) & 15) << 3))] = f2bf(v.y);
        tile[(si + 2) * 136 + (bi ^ (((si + 2) & 15) << 3))] = f2bf(v.z);
        tile[(si + 3) * 136 + (bi ^ (((si + 3) & 15) << 3))] = f2bf(v.w);
    }
    __syncthreads();
    // store: 1024 x 16B (64 s x 16 bi-octets); 4 per thread, fully coalesced
#pragma unroll
    for (int k = 0; k < 4; ++k) {
        const int j  = t + k * 256;
        const int sI = j >> 4, g = j & 15;
        const uint4 val = *(const uint4*)&tile[sI * 136 + ((g ^ (sI & 15)) << 3)];
        *(uint4*)(xbfT + (size_t)(s0 + sI) * 128 + g * 8) = val;
    }
}

// ---------------------------------------------------------------------------
// Pre-pass 2: W fp32 [oc][k] -> bf16 prepacked fragment image:
//   Wbf[(kpg*128+oc)*8 + j]   (k = kpg*8 + j, kpg = 0..31)
// ---------------------------------------------------------------------------
__global__ void prep_w_kernel(const float* __restrict__ W,
                              ushortT* __restrict__ Wbf)
{
    int idx = blockIdx.x * 256 + threadIdx.x;   // 32768 total
    int oc = idx >> 8, k = idx & 255;
    int kpg = k >> 3, j = k & 7;
    Wbf[((size_t)kpg * 128 + oc) * 8 + j] = f2bf(W[idx]);
}

// ---------------------------------------------------------------------------
// Fused MFMA kernel, 512 threads (8 waves). Wave w owns a 64x32 C quadrant:
// rows [64*(w>>2), +64) x cols [32*(w&3), +32) as 4x2 tiles of 16x16.
//
// v11 = v7 (proven 134us: single pixel, lgkm-only barriers, DPP routing)
// with the GEMM ring widened to 4 bufs, TWO chunks per barrier period:
//   pre: load ch0-3; store 0->b0, 1->b1; load ch4,5; BAR
//   P0: compute ch0(b0), ch1(b1); store 2->b2, 3->b3; load ch6,7; BAR
//   P1: compute ch2(b2), ch3(b3); store 4->b0, 5->b1;             BAR
//   P2: compute ch4(b0), ch5(b1); store 6->b2, 7->b3;             BAR
//   P3: compute ch6(b2), ch7(b3)   [4 barriers + pre vs v7's 9]
// Race-check: every buffer rewrite is >=1 barrier after its last read;
// every read >=1 barrier after its write. Load->store cover >= 2 periods.
// Peak A-prefetch regs: 4x uint4 (+8 VGPR vs v7; ~56 total, <=64 cap so
// (512,4) keeps 8-waves/SIMD eligibility WITHOUT spill — v8/v9 lesson:
// arg2={8,4} => VGPR cap {32,64}; count live state first).
// C/D: col=lane&15 -> oc-col c, row=4*quad+reg -> (b,i). direct_out write.
// ---------------------------------------------------------------------------
__launch_bounds__(512, 4)
__global__ void capsconv_mfma(const ushortT* __restrict__ xbfT,
                              const ushortT* __restrict__ Wbf,
                              const float* __restrict__ bias,
                              float* __restrict__ outbuf,
                              const int direct_out)
{
    __shared__ __align__(16) ushortT As[4][4 * 128 * 8];   // 4 x 8 KB ring
    __shared__ float cijs[64];       // [o][i]
    __shared__ float bijs[64];       // [o][i] (wave 0 only)
    __shared__ float aTmp[16 * 64];  // [b][o*8+i]

    const int t  = threadIdx.x;      // 0..511
    const int g8 = blockIdx.x;
    int p = (g8 & 7) * 529 + (g8 >> 3);     // XCD-contiguous pixel strips
    if (p >= NPIX) return;

    const int w  = t >> 6;       // wave id 0..7
    const int ln = t & 63;
    const int q  = ln >> 4;      // quad
    const int cL = ln & 15;      // lane col (c within tile)
    const int h  = q & 1;        // i-half
    const int mrow_base = 64 * (w >> 2);   // 0 or 64
    const int ncol_base = 32 * (w & 3);    // 0,32,64,96

    const int px = p / OWH;
    const int py = p % OWH;
    const int row0 = 2 * px - 2;
    const int col0 = 2 * py - 2;

    f32x4 acc[4][2];
#pragma unroll
    for (int mt = 0; mt < 4; ++mt)
#pragma unroll
        for (int nt = 0; nt < 2; ++nt) acc[mt][nt] = (f32x4){0.f, 0.f, 0.f, 0.f};

    // ---- A staging map (per thread, chunk-invariant except source ci) ----
    const int g     = t & 15;        // bi octet
    const int sI    = t >> 4;        // 0..31
    const int colw  = sI & 3;
    const int rowl  = (sI >> 2) & 3;
    const int cih   = sI >> 4;       // 0..1
    const int srow  = row0 + rowl;
    const int scol  = col0 + colw;
    const bool ok   = (srow >= 0 && srow < WH && scol >= 0 && scol < WH);
    const size_t aoff0 = ok
        ? ((size_t)((cih * WH + srow) * WH + scol) * 128 + g * 8)
        : 0;
    // LDS dest (bytes within As[buf]); bits 4-6 of wbase are zero.
    const int kpg   = cih * 2 + (rowl >> 1);
    const int jj    = (rowl & 1) * 4 + colw;
    const int wbase = (kpg * 128 + g * 8) * 16 + jj * 2;
    const int gk7   = g & 7;

    // fragment read byte offsets (swizzled), chunk-invariant
    int aRd[4];
#pragma unroll
    for (int mt = 0; mt < 4; ++mt) {
        const int by = (q * 128 + mrow_base + mt * 16 + cL) * 16;
        aRd[mt] = by ^ (((by >> 7) & 7) << 4);
    }

    uint4 aR0, aR1, aR2, aR3;   // up to 4 pending A loads

    auto loadA = [&](uint4& r, int kc) {
        r = make_uint4(0u, 0u, 0u, 0u);
        if (ok) r = *(const uint4*)(xbfT + aoff0 + (size_t)kc * (2 * WH * WH * 128));
    };
    auto storeA = [&](int buf, const uint4& r) {
        char* ab = (char*)&As[buf][0];
        const ushortT* av = (const ushortT*)&r;
#pragma unroll
        for (int c = 0; c < 8; ++c)
            *(ushortT*)(ab + wbase + ((c ^ gk7) << 4)) = av[c];
    };
    auto compute = [&](int kc, int buf) {
        const char* abase = (const char*)&As[buf][0];
        bf16x8 af[4], bfr[2];
#pragma unroll
        for (int mt = 0; mt < 4; ++mt)
            af[mt] = *(const bf16x8*)(abase + aRd[mt]);
        // B direct from global (L2-hot, no barrier dependency)
        const ushortT* bsrc = Wbf + kc * 4096 + (q * 128 + ncol_base + cL) * 8;
        bfr[0] = *(const bf16x8*)(bsrc);
        bfr[1] = *(const bf16x8*)(bsrc + 128);
#pragma unroll
        for (int mt = 0; mt < 4; ++mt)
#pragma unroll
            for (int nt = 0; nt < 2; ++nt)
                acc[mt][nt] = __builtin_amdgcn_mfma_f32_16x16x32_bf16(
                    af[mt], bfr[nt], acc[mt][nt], 0, 0, 0);
    };

    // ---------------- GEMM: ring-4, 2 chunks per barrier ----------------
    loadA(aR0, 0); loadA(aR1, 1); loadA(aR2, 2); loadA(aR3, 3);
    storeA(0, aR0);            // counted vmcnt waits land on first use
    storeA(1, aR1);
    loadA(aR0, 4); loadA(aR1, 5);
    LDS_BARRIER();             // b0,b1 ready; ch2-5 in flight

    compute(0, 0); compute(1, 1);
    storeA(2, aR2); storeA(3, aR3);
    loadA(aR2, 6); loadA(aR3, 7);
    LDS_BARRIER();             // b2,b3 ready; b0,b1 reads done

    compute(2, 2); compute(3, 3);
    storeA(0, aR0); storeA(1, aR1);
    LDS_BARRIER();             // b0,b1 (ch4,5) ready; b2,b3 reads done

    compute(4, 0); compute(5, 1);
    storeA(2, aR2); storeA(3, aR3);
    LDS_BARRIER();             // b2,b3 (ch6,7) ready

    compute(6, 2); compute(7, 3);

    // bias epilogue
#pragma unroll
    for (int nt = 0; nt < 2; ++nt) {
        const float bv = bias[ncol_base + nt * 16 + cL];
#pragma unroll
        for (int mt = 0; mt < 4; ++mt) acc[mt][nt] += bv;
    }

    // ---------------- dynamic routing (3 iters) ----------------
    // iter 0: b_ij = 0 -> c_ij = 1/8 exactly (no softmax needed).
    for (int it = 0; it < 3; ++it) {
        float4 cf4[2];
        if (it == 0) {
#pragma unroll
            for (int nt = 0; nt < 2; ++nt)
                cf4[nt] = make_float4(0.125f, 0.125f, 0.125f, 0.125f);
        } else {
#pragma unroll
            for (int nt = 0; nt < 2; ++nt)
                cf4[nt] = *(const float4*)&cijs[(2 * (w & 3) + nt) * 8 + 4 * h];
        }

#pragma unroll
        for (int mt = 0; mt < 4; ++mt) {
            const int b = 8 * (w >> 2) + 2 * mt + (q >> 1);
#pragma unroll
            for (int nt = 0; nt < 2; ++nt) {
                const int o = 2 * (w & 3) + nt;
                const float4 cf = cf4[nt];
                float sp = cf.x * acc[mt][nt][0] + cf.y * acc[mt][nt][1]
                         + cf.z * acc[mt][nt][2] + cf.w * acc[mt][nt][3];
                float s = sp + __shfl_xor(sp, 16);
                // ssq over the 16 cL lanes (DPP, VALU-only)
                float ssq = s * s;
                ssq += dppMov<0xB1>(ssq);
                ssq += dppMov<0x4E>(ssq);
                ssq += dppMov<0x124>(ssq);
                ssq += dppMov<0x128>(ssq);
                const float scale = sqrtf(ssq) * __builtin_amdgcn_rcpf(1.f + ssq);
                const float vj = s * scale;

                if (it == 2) {
                    if (q == 0 || q == 2) {
                        if (direct_out)
                            outbuf[(size_t)(b * NOC + o * 16 + cL) * NPIX + p] = vj;
                        else
                            outbuf[(size_t)p * 2048 + b * NOC + o * 16 + cL] = vj;
                    }
                } else {
                    // fold: rows -> lanes; lane cL ends with row (cL&3)
                    f32x4 ap = acc[mt][nt] * vj;
                    const bool k1 = (cL & 1) != 0;
                    float e0 = k1 ? ap[1] : ap[0];
                    float o0 = k1 ? ap[0] : ap[1];
                    float e1 = k1 ? ap[3] : ap[2];
                    float o1 = k1 ? ap[2] : ap[3];
                    e0 += dppMov<0xB1>(o0);
                    e1 += dppMov<0xB1>(o1);
                    const bool k2 = (cL & 2) != 0;
                    float f0 = k2 ? e1 : e0;
                    float f1 = k2 ? e0 : e1;
                    f0 += dppMov<0x4E>(f1);
                    f0 += dppMov<0x124>(f0);
                    f0 += dppMov<0x128>(f0);
                    if (cL < 4)
                        aTmp[b * 64 + o * 8 + 4 * h + cL] = f0;
                }
            }
        }
        if (it < 2) {
            LDS_BARRIER();   // aTmp writes visible (lgkm-only: no vmem deps)
            if (t < 64) {
                float sum = 0.f;
#pragma unroll
                for (int b = 0; b < BB; ++b) sum += aTmp[b * 64 + t];
                float bij = (it == 0 ? 0.f : bijs[t]) + sum * (1.f / 16.f);
                bijs[t] = bij;
                float mx = bij;
                mx = fmaxf(mx, __shfl_xor(mx, 1));
                mx = fmaxf(mx, __shfl_xor(mx, 2));
                mx = fmaxf(mx, __shfl_xor(mx, 4));
                float e = __expf(bij - mx);
                float se = e;
                se += __shfl_xor(se, 1);
                se += __shfl_xor(se, 2);
                se += __shfl_xor(se, 4);
                cijs[t] = e * __builtin_amdgcn_rcpf(se);
            }
            LDS_BARRIER();
        }
    }
}

// ---------------------------------------------------------------------------
// [pixel][boc] -> [boc][pixel] tiled transpose (fallback path only)
// ---------------------------------------------------------------------------
__global__ void transpose_kernel(const float* __restrict__ vtmp,
                                 float* __restrict__ out)
{
    __shared__ float tile[32][33];
    const int bp = blockIdx.x;
    const int bc = blockIdx.y;
    const int p0 = bp * 32, c0 = bc * 32;
    const int tx = threadIdx.x & 31, ty = threadIdx.x >> 5;

    for (int r = ty; r < 32; r += 8) {
        const int p = p0 + r;
        tile[r][tx] = (p < NPIX) ? vtmp[(size_t)p * 2048 + c0 + tx] : 0.f;
    }
    __syncthreads();
    for (int r = ty; r < 32; r += 8) {
        const int c = c0 + r;
        const int p = p0 + tx;
        if (p < NPIX) out[(size_t)c * NPIX + p] = tile[tx][r];
    }
}

// ---------------------------------------------------------------------------
// Round-1 fp32 fallback (proven correct) — used only if ws too small
// ---------------------------------------------------------------------------
__launch_bounds__(256, 2)
__global__ void capsconv_fp32(const float* __restrict__ x,
                              const float* __restrict__ Wc,
                              const float* __restrict__ bias,
                              float* __restrict__ outbuf,
                              const int direct_out)
{
    __shared__ float As[KC][BI];
    __shared__ float Bsh[KC][NOC];
    __shared__ float cij[64];
    __shared__ float bijs2[64];
    __shared__ float aTmp2[BB * 64];

    const int t  = threadIdx.x;
    const int tn = t & 15;
    const int tm = t >> 4;
    const int p  = blockIdx.x;
    const int px = p / OWH;
    const int py = p % OWH;
    const int row0 = 2 * px - 2;
    const int col0 = 2 * py - 2;
    const bool interior = (px >= 1 && px <= 63 && py >= 1 && py <= 63);

    float C[8][8];
#pragma unroll
    for (int r = 0; r < 8; ++r)
#pragma unroll
        for (int j = 0; j < 8; ++j) C[r][j] = 0.f;

    float areg[8][4];
    float breg[32];

    auto load_chunk = [&](int kc) {
#pragma unroll
        for (int g = 0; g < 8; ++g) {
            const int L    = g * 256 + t;
            const int bi   = L & 127;
            const int cikw = L >> 7;
            const int ci   = kc * 4 + (cikw >> 2);
            const int kw   = cikw & 3;
            const int row  = row0 + kw;
            const float* src = x + (((size_t)(bi * CIN + ci) * WH + row) * WH + col0);
            if (interior) {
                const float2 v01 = *(const float2*)(src);
                const float2 v23 = *(const float2*)(src + 2);
                areg[g][0] = v01.x; areg[g][1] = v01.y;
                areg[g][2] = v23.x; areg[g][3] = v23.y;
            } else {
#pragma unroll
                for (int kh = 0; kh < 4; ++kh) {
                    const int col = col0 + kh;
                    areg[g][kh] = (row >= 0 && row < WH && col >= 0 && col < WH)
                                      ? src[kh] : 0.f;
                }
            }
        }
        {
            const int oc  = t >> 1;
            const int kk0 = (t & 1) * 32;
            const float* wsrc = Wc + (size_t)oc * KTOT + kc * KC + kk0;
#pragma unroll
            for (int m = 0; m < 32; m += 4) {
                const float4 v = *(const float4*)(wsrc + m);
                breg[m] = v.x; breg[m+1] = v.y; breg[m+2] = v.z; breg[m+3] = v.w;
            }
        }
    };

    load_chunk(0);
    for (int kc = 0; kc < NCHUNK; ++kc) {
        __syncthreads();
#pragma unroll
        for (int g = 0; g < 8; ++g) {
            const int L    = g * 256 + t;
            const int bi   = L & 127;
            const int cikw = L >> 7;
            const int kkb  = cikw * 4;
#pragma unroll
            for (int kh = 0; kh < 4; ++kh) As[kkb + kh][bi] = areg[g][kh];
        }
        {
            const int oc  = t >> 1;
            const int kk0 = (t & 1) * 32;
#pragma unroll
            for (int m = 0; m < 32; ++m) Bsh[kk0 + m][oc] = breg[m];
        }
        __syncthreads();
        if (kc < NCHUNK - 1) load_chunk(kc + 1);
#pragma unroll 4
        for (int k = 0; k < KC; ++k) {
            float af[8], bf[8];
            *(float4*)(af)     = *(const float4*)&As[k][tm * 8];
            *(float4*)(af + 4) = *(const float4*)&As[k][tm * 8 + 4];
            *(float4*)(bf)     = *(const float4*)&Bsh[k][tn * 8];
            *(float4*)(bf + 4) = *(const float4*)&Bsh[k][tn * 8 + 4];
#pragma unroll
            for (int r = 0; r < 8; ++r)
#pragma unroll
                for (int j = 0; j < 8; ++j)
                    C[r][j] = fmaf(af[r], bf[j], C[r][j]);
        }
    }
#pragma unroll
    for (int j = 0; j < 8; ++j) {
        const float bj = bias[tn * 8 + j];
#pragma unroll
        for (int r = 0; r < 8; ++r) C[r][j] += bj;
    }

    const int o = tn >> 1;
    __syncthreads();
    if (t < 64) bijs2[t] = 0.f;

    float vout[8];
    for (int it = 0; it < 3; ++it) {
        __syncthreads();
        if (t < 8) {
            const int oo = t;
            float mx = -1e30f;
#pragma unroll
            for (int i = 0; i < 8; ++i) mx = fmaxf(mx, bijs2[i * 8 + oo]);
            float e[8]; float ssum = 0.f;
#pragma unroll
            for (int i = 0; i < 8; ++i) { e[i] = expf(bijs2[i * 8 + oo] - mx); ssum += e[i]; }
            const float inv = 1.f / ssum;
#pragma unroll
            for (int i = 0; i < 8; ++i) cij[i * 8 + oo] = e[i] * inv;
        }
        __syncthreads();
        float cf[8];
#pragma unroll
        for (int i = 0; i < 8; ++i) cf[i] = cij[i * 8 + o];
        float s[8];
#pragma unroll
        for (int j = 0; j < 8; ++j) {
            float acc = 0.f;
#pragma unroll
            for (int r = 0; r < 8; ++r) acc = fmaf(cf[r], C[r][j], acc);
            s[j] = acc;
        }
        float ssq = 0.f;
#pragma unroll
        for (int j = 0; j < 8; ++j) ssq = fmaf(s[j], s[j], ssq);
        ssq += __shfl_xor(ssq, 1);
        const float scale = ssq / ((1.f + ssq) * sqrtf(ssq));
        if (it == 2) {
#pragma unroll
            for (int j = 0; j < 8; ++j) vout[j] = s[j] * scale;
        } else {
            float ap[8];
#pragma unroll
            for (int r = 0; r < 8; ++r) {
                float acc = 0.f;
#pragma unroll
                for (int j = 0; j < 8; ++j) acc = fmaf(C[r][j], s[j] * scale, acc);
                ap[r] = acc;
            }
#pragma unroll
            for (int r = 0; r < 8; ++r) ap[r] += __shfl_xor(ap[r], 1);
            if ((tn & 1) == 0) {
#pragma unroll
                for (int r = 0; r < 8; ++r) aTmp2[tm * 64 + r * 8 + o] = ap[r];
            }
            __syncthreads();
            if (t < 64) {
                float acc = 0.f;
#pragma unroll
                for (int b = 0; b < BB; ++b) acc += aTmp2[b * 64 + t];
                bijs2[t] += acc * (1.f / 16.f);
            }
        }
    }
    if (direct_out) {
#pragma unroll
        for (int j = 0; j < 8; ++j)
            outbuf[(size_t)(tm * NOC + tn * 8 + j) * NPIX + p] = vout[j];
    } else {
        float4* dst = (float4*)(outbuf + (size_t)p * 2048 + tm * NOC + tn * 8);
        dst[0] = make_float4(vout[0], vout[1], vout[2], vout[3]);
        dst[1] = make_float4(vout[4], vout[5], vout[6], vout[7]);
    }
}

extern "C" void kernel_launch(void* const* d_in, const int* in_sizes, int n_in,
                              void* d_out, int out_size, void* d_ws, size_t ws_size,
                              hipStream_t stream)
{
    const float* x    = (const float*)d_in[0];
    const float* Wc   = (const float*)d_in[1];
    const float* bias = (const float*)d_in[2];
    float* out        = (float*)d_out;

    const size_t VT_BYTES = (size_t)NPIX * 2048 * sizeof(float);   // 34,611,200
    const size_t WB_OFF   = VT_BYTES;
    const size_t XB_OFF   = WB_OFF + 65536;
    const size_t TOTAL    = XB_OFF + (size_t)BI * CIN * WH * WH * 2;  // 101,785,600

    if (ws_size >= TOTAL) {
        ushortT* Wbf  = (ushortT*)((char*)d_ws + WB_OFF);
        ushortT* xbfT = (ushortT*)((char*)d_ws + XB_OFF);

        cvtT_kernel<<<S_TOTAL / 64, 256, 0, stream>>>(x, xbfT);
        prep_w_kernel<<<128, 256, 0, stream>>>(Wc, Wbf);
        capsconv_mfma<<<529 * 8, 512, 0, stream>>>(xbfT, Wbf, bias, out, 1);
    } else if (ws_size >= VT_BYTES) {
        float* vtmp = (float*)d_ws;
        capsconv_fp32<<<NPIX, 256, 0, stream>>>(x, Wc, bias, vtmp, 0);
        dim3 g((NPIX + 31) / 32, 2048 / 32);
        transpose_kernel<<<g, 256, 0, stream>>>(vtmp, out);
    } else {
        capsconv_fp32<<<NPIX, 256, 0, stream>>>(x, Wc, bias, out, 1);
    }
}